// Round 13
// baseline (324.761 us; speedup 1.0000x reference)
//
#include <hip/hip_runtime.h>

#define MAXSLICE 12544   // max nodes per slice (node-level tier-B path)
#define MAXSUB   800     // max 16-node subbuckets per slice (>= 12544/16)
#define NBH 32           // histogram/place chunks per slice
#define IDXCAP 512       // per-chunk in-fused sort capacity

static __device__ __forceinline__ float relu_f(float v) { return fmaxf(v, 0.f); }

// fp32 -> bf16 with round-to-nearest-even
static __device__ __forceinline__ unsigned short f2bf(float f) {
  unsigned u = __float_as_uint(f);
  u += 0x7fffu + ((u >> 16) & 1u);
  return (unsigned short)(u >> 16);
}
static __device__ __forceinline__ float bf2f(unsigned short h) {
  return __uint_as_float(((unsigned)h) << 16);
}

// ===== Mega-kernel (tier A, HW-verified R11 @236.9): blocks < nbn do GEMM;
// rest do packed bin. pk = col | rloc<<17 (n_nodes < 2^17), ew planar. =====
__global__ __launch_bounds__(256) void k_gemm_bin(
    const float* __restrict__ x, const float* __restrict__ mk,
    const float* __restrict__ sk, const float* __restrict__ bias,
    unsigned short* __restrict__ xwh, float* __restrict__ out, int n_nodes,
    const int* __restrict__ row, const int* __restrict__ col,
    const float* __restrict__ ew,
    int* __restrict__ bpk, float* __restrict__ bew, int* __restrict__ bcur,
    int n_edges, int sliceN, int cap, int nbn)
{
  __shared__ union U {
    struct { float mks[64][64]; float sks[64][64]; float xT[64][68]; } g;
    struct { int wcnt[4][8]; int tot[8]; int toff[8]; int gaddr[8];
             int pk[1024]; float ww[1024]; } b;
  } u;
  const int tid = threadIdx.x;

  if (blockIdx.x < nbn) {
    // ---- GEMM path ----
    for (int i = tid; i < 4096; i += 256) {
      u.g.mks[i >> 6][i & 63] = mk[i];
      u.g.sks[i >> 6][i & 63] = sk[i];
    }
    const int node0 = blockIdx.x * 64;
    for (int i = tid; i < 4096; i += 256) {
      int nl = i >> 6, f = i & 63;
      int n = node0 + nl;
      u.g.xT[f][nl] = (n < n_nodes) ? x[(size_t)n * 64 + f] : 0.f;
    }
    __syncthreads();
    const int g  = tid >> 4;
    const int ub = (tid & 15) * 4;
    float am[4][4] = {{0.f}};
    float as[4][4] = {{0.f}};
    for (int f = 0; f < 64; ++f) {
      float4 wm = *(const float4*)&u.g.mks[f][ub];
      float4 ws = *(const float4*)&u.g.sks[f][ub];
      float4 xv = *(const float4*)&u.g.xT[f][4 * g];
      const float xs[4] = {xv.x, xv.y, xv.z, xv.w};
#pragma unroll
      for (int j = 0; j < 4; ++j) {
        am[j][0] += xs[j] * wm.x; am[j][1] += xs[j] * wm.y;
        am[j][2] += xs[j] * wm.z; am[j][3] += xs[j] * wm.w;
        as[j][0] += xs[j] * ws.x; as[j][1] += xs[j] * ws.y;
        as[j][2] += xs[j] * ws.z; as[j][3] += xs[j] * ws.w;
      }
    }
    float4 bv = *(const float4*)&bias[64 + ub];
#pragma unroll
    for (int j = 0; j < 4; ++j) {
      int n = node0 + 4 * g + j;
      if (n >= n_nodes) break;
      ushort4 o1 = make_ushort4(f2bf(am[j][0]), f2bf(am[j][1]),
                                f2bf(am[j][2]), f2bf(am[j][3]));
      *(ushort4*)&xwh[(size_t)n * 64 + ub] = o1;
      *(float4*)&out[(size_t)n * 128 + 64 + ub] =
          make_float4(relu_f(as[j][0] + bv.x), relu_f(as[j][1] + bv.y),
                      relu_f(as[j][2] + bv.z), relu_f(as[j][3] + bv.w));
    }
    return;
  }

  // ---- BIN path (packed records) ----
  const int vbid = blockIdx.x - nbn;
  const int nvb  = gridDim.x - nbn;
  const int wave = tid >> 6;
  const int lane = tid & 63;
  const unsigned usliceN = (unsigned)sliceN;
  const int stride = nvb * 1024;
  for (int e0 = vbid * 1024; e0 < n_edges; e0 += stride) {
    const int e = e0 + 4 * tid;
    int   pp[4];
    float ww[4];
    int   ss[4];
    if (e + 3 < n_edges) {
      int4 r4   = *(const int4*)&row[e];
      int4 c4   = *(const int4*)&col[e];
      float4 w4 = *(const float4*)&ew[e];
      int rr[4] = {r4.x, r4.y, r4.z, r4.w};
      int cc[4] = {c4.x, c4.y, c4.z, c4.w};
      ww[0] = w4.x; ww[1] = w4.y; ww[2] = w4.z; ww[3] = w4.w;
#pragma unroll
      for (int j = 0; j < 4; ++j) {
        ss[j] = (int)((unsigned)rr[j] / usliceN);
        pp[j] = cc[j] | ((rr[j] - ss[j] * sliceN) << 17);
      }
    } else {
#pragma unroll
      for (int j = 0; j < 4; ++j) {
        int ej = e + j;
        bool v = ej < n_edges;
        int r = v ? row[ej] : 0;
        int c = v ? col[ej] : 0;
        ww[j] = v ? ew[ej] : 0.f;
        ss[j] = v ? (int)((unsigned)r / usliceN) : -1;
        pp[j] = v ? (c | ((r - ss[j] * sliceN) << 17)) : 0;
      }
    }
#pragma unroll
    for (int b = 0; b < 8; ++b) {
      int c = 0;
#pragma unroll
      for (int j = 0; j < 4; ++j) c += __popcll(__ballot(ss[j] == b));
      if (lane == 0) u.b.wcnt[wave][b] = c;
    }
    __syncthreads();
    if (wave == 0 && lane < 8) {
      const int b = lane;
      int t0 = u.b.wcnt[0][b], t1 = u.b.wcnt[1][b];
      int t2 = u.b.wcnt[2][b], t3 = u.b.wcnt[3][b];
      int tot = t0 + t1 + t2 + t3;
      u.b.tot[b] = tot;
      u.b.wcnt[0][b] = 0;
      u.b.wcnt[1][b] = t0;
      u.b.wcnt[2][b] = t0 + t1;
      u.b.wcnt[3][b] = t0 + t1 + t2;
      int gbase = tot ? atomicAdd(&bcur[b], tot) : 0;
      int pre = 0;
#pragma unroll
      for (int j2 = 0; j2 < 8; ++j2) pre += (j2 < b) ? u.b.tot[j2] : 0;
      u.b.toff[b]  = pre;
      u.b.gaddr[b] = b * cap + gbase - pre;
    }
    __syncthreads();
#pragma unroll
    for (int b = 0; b < 8; ++b) {
      const int sb = u.b.toff[b] + u.b.wcnt[wave][b];
      int off_local = 0;
#pragma unroll
      for (int j = 0; j < 4; ++j) {
        unsigned long long mm = __ballot(ss[j] == b);
        if (ss[j] == b) {
          int rank = __popcll(mm & ((1ull << lane) - 1ull));
          int slot = sb + off_local + rank;
          u.b.pk[slot] = pp[j];
          u.b.ww[slot] = ww[j];
        }
        off_local += __popcll(mm);
      }
    }
    __syncthreads();
    const int total = u.b.toff[7] + u.b.tot[7];
    for (int i2 = tid; i2 < total; i2 += 256) {
      int b = 0;
#pragma unroll
      for (int j2 = 1; j2 < 8; ++j2) b += (i2 >= u.b.toff[j2]) ? 1 : 0;
      int a = u.b.gaddr[b] + i2;
      if (a < (b + 1) * cap) {
        bpk[a] = u.b.pk[i2];
        bew[a] = u.b.ww[i2];
      }
    }
    __syncthreads();
  }
}

// Standalone GEMM (tiers B/C)
__global__ __launch_bounds__(256) void k_node_dual_gemm(
    const float* __restrict__ x, const float* __restrict__ mk,
    const float* __restrict__ sk, const float* __restrict__ bias,
    unsigned short* __restrict__ xwh, float* __restrict__ out, int n_nodes)
{
  __shared__ float s_mk[64][64];
  __shared__ float s_sk[64][64];
  __shared__ float s_xT[64][68];
  const int tid = threadIdx.x;
  for (int i = tid; i < 4096; i += 256) {
    s_mk[i >> 6][i & 63] = mk[i];
    s_sk[i >> 6][i & 63] = sk[i];
  }
  const int node0 = blockIdx.x * 64;
  for (int i = tid; i < 4096; i += 256) {
    int nl = i >> 6, f = i & 63;
    int n = node0 + nl;
    s_xT[f][nl] = (n < n_nodes) ? x[(size_t)n * 64 + f] : 0.f;
  }
  __syncthreads();
  const int g  = tid >> 4;
  const int ub = (tid & 15) * 4;
  float am[4][4] = {{0.f}};
  float as[4][4] = {{0.f}};
  for (int f = 0; f < 64; ++f) {
    float4 wm = *(const float4*)&s_mk[f][ub];
    float4 ws = *(const float4*)&s_sk[f][ub];
    float4 xv = *(const float4*)&s_xT[f][4 * g];
    const float xs[4] = {xv.x, xv.y, xv.z, xv.w};
#pragma unroll
    for (int j = 0; j < 4; ++j) {
      am[j][0] += xs[j] * wm.x; am[j][1] += xs[j] * wm.y;
      am[j][2] += xs[j] * wm.z; am[j][3] += xs[j] * wm.w;
      as[j][0] += xs[j] * ws.x; as[j][1] += xs[j] * ws.y;
      as[j][2] += xs[j] * ws.z; as[j][3] += xs[j] * ws.w;
    }
  }
  float4 bv = *(const float4*)&bias[64 + ub];
#pragma unroll
  for (int j = 0; j < 4; ++j) {
    int n = node0 + 4 * g + j;
    if (n >= n_nodes) break;
    ushort4 o1 = make_ushort4(f2bf(am[j][0]), f2bf(am[j][1]),
                              f2bf(am[j][2]), f2bf(am[j][3]));
    *(ushort4*)&xwh[(size_t)n * 64 + ub] = o1;
    *(float4*)&out[(size_t)n * 128 + 64 + ub] =
        make_float4(relu_f(as[j][0] + bv.x), relu_f(as[j][1] + bv.y),
                    relu_f(as[j][2] + bv.z), relu_f(as[j][3] + bv.w));
  }
}

// ---------- tier C (original path) ----------
__global__ __launch_bounds__(256) void k_count(
    const int* __restrict__ row, int* __restrict__ cnt, int n_edges)
{
  int e = blockIdx.x * 256 + threadIdx.x;
  if (e < n_edges) atomicAdd(&cnt[row[e]], 1);
}

__global__ __launch_bounds__(256) void k_build_sliced(
    const int* __restrict__ row, const int* __restrict__ col,
    const float* __restrict__ ew, int* __restrict__ off,
    int2* __restrict__ elist, int n_edges, int n_nodes)
{
  const int slice = blockIdx.x & 7;
  const int vb    = blockIdx.x >> 3;
  const int nvb   = gridDim.x >> 3;
  const int sliceN = (n_nodes + 7) >> 3;
  const int lo = slice * sliceN;
  const int hi = min(lo + sliceN, n_nodes);
  for (int e = vb * 256 + threadIdx.x; e < n_edges; e += nvb * 256) {
    int r = row[e];
    if (r >= lo && r < hi) {
      int pos = atomicAdd(&off[r], 1);
      elist[pos] = make_int2(col[e], __float_as_int(ew[e]));
    }
  }
}
// ---------- end tier C ----------

// Scan step 1: per-1024-block sums of cnt.
__global__ __launch_bounds__(1024) void k_bsum(
    const int* __restrict__ cnt, int* __restrict__ bsum, int n)
{
  __shared__ int s[1024];
  int tid = threadIdx.x;
  int i = blockIdx.x * 1024 + tid;
  s[tid] = (i < n) ? cnt[i] : 0;
  __syncthreads();
  for (int d = 512; d > 0; d >>= 1) {
    if (tid < d) s[tid] += s[tid + d];
    __syncthreads();
  }
  if (tid == 0) bsum[blockIdx.x] = s[0];
}

// Scan step 2: block-local exclusive scan of cnt + block prefix from bsum.
__global__ __launch_bounds__(1024) void k_boffs(
    const int* __restrict__ cnt, const int* __restrict__ bsum,
    int* __restrict__ off, int n, int nb)
{
  __shared__ int s[1024];
  __shared__ int sp[128];
  int tid = threadIdx.x;
  if (tid < 128) {
    int acc = 0;
    for (int j = tid; j < blockIdx.x && j < nb; j += 128) acc += bsum[j];
    sp[tid] = acc;
  }
  int i = blockIdx.x * 1024 + tid;
  int v = (i < n) ? cnt[i] : 0;
  s[tid] = v;
  __syncthreads();
  for (int d = 64; d > 0; d >>= 1) {
    if (tid < d) sp[tid] += sp[tid + d];
    __syncthreads();
  }
  for (int d = 1; d < 1024; d <<= 1) {
    int t = (tid >= d) ? s[tid - d] : 0;
    __syncthreads();
    s[tid] += t;
    __syncthreads();
  }
  if (i < n) off[i] = s[tid] - v + sp[0];
}

// Pass B (tier B, full records): [HW-verified R6/R7/R8]
__global__ __launch_bounds__(256) void k_bin(
    const int* __restrict__ row, const int* __restrict__ col,
    const float* __restrict__ ew,
    int* __restrict__ brow, int2* __restrict__ bpair,
    int* __restrict__ bcur, int n_edges, int sliceN, int cap)
{
  __shared__ int  s_wcnt[4][8];
  __shared__ int  s_tot[8];
  __shared__ int  s_toff[8];
  __shared__ int  s_gaddr[8];
  __shared__ int  s_rowst[1024];
  __shared__ int2 s_pairst[1024];
  const int tid  = threadIdx.x;
  const int wave = tid >> 6;
  const int lane = tid & 63;
  const unsigned usliceN = (unsigned)sliceN;
  const int stride = gridDim.x * 1024;
  for (int e0 = blockIdx.x * 1024; e0 < n_edges; e0 += stride) {
    const int e = e0 + 4 * tid;
    int   rr[4], cc[4];
    float ww[4];
    int   ss[4];
    if (e + 3 < n_edges) {
      int4 r4   = *(const int4*)&row[e];
      int4 c4   = *(const int4*)&col[e];
      float4 w4 = *(const float4*)&ew[e];
      rr[0] = r4.x; rr[1] = r4.y; rr[2] = r4.z; rr[3] = r4.w;
      cc[0] = c4.x; cc[1] = c4.y; cc[2] = c4.z; cc[3] = c4.w;
      ww[0] = w4.x; ww[1] = w4.y; ww[2] = w4.z; ww[3] = w4.w;
#pragma unroll
      for (int j = 0; j < 4; ++j) ss[j] = (int)((unsigned)rr[j] / usliceN);
    } else {
#pragma unroll
      for (int j = 0; j < 4; ++j) {
        int ej = e + j;
        bool v = ej < n_edges;
        rr[j] = v ? row[ej] : 0;
        cc[j] = v ? col[ej] : 0;
        ww[j] = v ? ew[ej]  : 0.f;
        ss[j] = v ? (int)((unsigned)rr[j] / usliceN) : -1;
      }
    }
#pragma unroll
    for (int b = 0; b < 8; ++b) {
      int c = 0;
#pragma unroll
      for (int j = 0; j < 4; ++j) c += __popcll(__ballot(ss[j] == b));
      if (lane == 0) s_wcnt[wave][b] = c;
    }
    __syncthreads();
    if (wave == 0 && lane < 8) {
      const int b = lane;
      int t0 = s_wcnt[0][b], t1 = s_wcnt[1][b], t2 = s_wcnt[2][b], t3 = s_wcnt[3][b];
      int tot = t0 + t1 + t2 + t3;
      s_tot[b] = tot;
      s_wcnt[0][b] = 0;
      s_wcnt[1][b] = t0;
      s_wcnt[2][b] = t0 + t1;
      s_wcnt[3][b] = t0 + t1 + t2;
      int gbase = tot ? atomicAdd(&bcur[b], tot) : 0;
      int pre = 0;
#pragma unroll
      for (int j2 = 0; j2 < 8; ++j2) pre += (j2 < b) ? s_tot[j2] : 0;
      s_toff[b]  = pre;
      s_gaddr[b] = b * cap + gbase - pre;
    }
    __syncthreads();
#pragma unroll
    for (int b = 0; b < 8; ++b) {
      const int sb = s_toff[b] + s_wcnt[wave][b];
      int off_local = 0;
#pragma unroll
      for (int j = 0; j < 4; ++j) {
        unsigned long long mm = __ballot(ss[j] == b);
        if (ss[j] == b) {
          int rank = __popcll(mm & ((1ull << lane) - 1ull));
          int slot = sb + off_local + rank;
          s_rowst[slot]  = rr[j];
          s_pairst[slot] = make_int2(cc[j], __float_as_int(ww[j]));
        }
        off_local += __popcll(mm);
      }
    }
    __syncthreads();
    const int total = s_toff[7] + s_tot[7];
    for (int i2 = tid; i2 < total; i2 += 256) {
      int b = 0;
#pragma unroll
      for (int j2 = 1; j2 < 8; ++j2) b += (i2 >= s_toff[j2]) ? 1 : 0;
      int a = s_gaddr[b] + i2;
      if (a < (b + 1) * cap) {
        brow[a]  = s_rowst[i2];
        bpair[a] = s_pairst[i2];
      }
    }
    __syncthreads();
  }
}

// ===================== tier B (node-level CSR, proven R3 path) =====================
__global__ __launch_bounds__(256) void k_hist(
    const int* __restrict__ brow, const int* __restrict__ bcur,
    int* __restrict__ hist, int cap, int chunk, int sliceN)
{
  __shared__ int h[MAXSLICE];
  const int s   = blockIdx.x & 7;
  const int blk = blockIdx.x >> 3;
  const int tid = threadIdx.x;
  for (int i = tid; i < MAXSLICE; i += 256) h[i] = 0;
  __syncthreads();
  const int n_s  = min(bcur[s], cap);
  const int lo_e = blk * chunk;
  const int hi_e = min(lo_e + chunk, n_s);
  const int base = s * cap;
  const int lo   = s * sliceN;
  for (int i = lo_e + tid; i < hi_e; i += 256) {
    atomicAdd(&h[brow[base + i] - lo], 1);
  }
  __syncthreads();
  int* hrow = hist + (size_t)(s * NBH + blk) * MAXSLICE;
  for (int i = tid; i < MAXSLICE / 4; i += 256) {
    ((int4*)hrow)[i] = ((const int4*)h)[i];
  }
}

__global__ __launch_bounds__(256) void k_colscan(
    int* __restrict__ hist, int* __restrict__ cnt, int sliceN, int n_nodes)
{
  const int s  = blockIdx.x & 7;
  const int cb = blockIdx.x >> 3;
  const int b0 = cb * 1024 + threadIdx.x * 4;
  if (b0 >= sliceN) return;
  int4 acc = make_int4(0, 0, 0, 0);
  int* hs = hist + (size_t)s * NBH * MAXSLICE;
#pragma unroll 4
  for (int blk = 0; blk < NBH; ++blk) {
    int4* p = (int4*)(hs + (size_t)blk * MAXSLICE + b0);
    int4 v = *p;
    *p = acc;
    acc.x += v.x; acc.y += v.y; acc.z += v.z; acc.w += v.w;
  }
  const int node = s * sliceN + b0;
  if (b0 + 3 < sliceN && node + 3 < n_nodes) {
    *(int4*)&cnt[node] = acc;
  } else {
    int a[4] = {acc.x, acc.y, acc.z, acc.w};
    for (int j = 0; j < 4; ++j)
      if (b0 + j < sliceN && node + j < n_nodes) cnt[node + j] = a[j];
  }
}

__global__ __launch_bounds__(256) void k_place(
    const int* __restrict__ brow, const int2* __restrict__ bpair,
    const int* __restrict__ bcur, const int* __restrict__ hist,
    const int* __restrict__ off, int2* __restrict__ elist,
    int cap, int chunk, int sliceN, int n_nodes)
{
  __shared__ int cur[MAXSLICE];
  const int s   = blockIdx.x & 7;
  const int blk = blockIdx.x >> 3;
  const int tid = threadIdx.x;
  const int lo  = s * sliceN;
  const int hi  = min(lo + sliceN, n_nodes);
  const int nb  = hi - lo;
  const int* hrow = hist + (size_t)(s * NBH + blk) * MAXSLICE;
  for (int i = tid; i < nb; i += 256) cur[i] = off[lo + i] + hrow[i];
  __syncthreads();
  const int n_s  = min(bcur[s], cap);
  const int lo_e = blk * chunk;
  const int hi_e = min(lo_e + chunk, n_s);
  const int base = s * cap;
  for (int i = lo_e + tid; i < hi_e; i += 256) {
    int r = brow[base + i] - lo;
    int p = atomicAdd(&cur[r], 1);
    elist[p] = bpair[base + i];
  }
}

// R3's proven fused kernel (tier B/C): per-node 16-lane groups, 8-deep unroll.
__global__ __launch_bounds__(256) void k_fused_csr(
    const int* __restrict__ cnt, const int* __restrict__ off,
    const int2* __restrict__ elist, const unsigned short* __restrict__ xwh,
    const float* __restrict__ mb, const float* __restrict__ nk,
    const float* __restrict__ bias, float* __restrict__ out, int n_nodes,
    int starts)
{
  __shared__ float s_nk[64][64];
  __shared__ float s_rh[16][68];
  const int tid = threadIdx.x;
  for (int i = tid; i < 1024; i += 256) {
    *(float4*)&s_nk[0][4 * i] = *(const float4*)&nk[4 * i];
  }
  const int node_l = tid >> 4;
  const int q = tid & 15;
  const int n = blockIdx.x * 16 + node_l;
  float4 acc = make_float4(0.f, 0.f, 0.f, 0.f);
  if (n < n_nodes) {
    const float4 mbq = *(const float4*)&mb[4 * q];
    const int c = cnt[n];
    int i = off[n] - (starts ? 0 : c);
    const int end = i + c;
    for (; i + 8 <= end; i += 8) {
      int2 e[8];
#pragma unroll
      for (int j = 0; j < 8; ++j) e[j] = elist[i + j];
      ushort4 u[8];
#pragma unroll
      for (int j = 0; j < 8; ++j)
        u[j] = *(const ushort4*)&xwh[(size_t)e[j].x * 64 + 4 * q];
#pragma unroll
      for (int j = 0; j < 8; ++j) {
        float w = __int_as_float(e[j].y);
        acc.x += relu_f(w * bf2f(u[j].x) + mbq.x);
        acc.y += relu_f(w * bf2f(u[j].y) + mbq.y);
        acc.z += relu_f(w * bf2f(u[j].z) + mbq.z);
        acc.w += relu_f(w * bf2f(u[j].w) + mbq.w);
      }
    }
    if (i + 4 <= end) {
      int2 e[4];
#pragma unroll
      for (int j = 0; j < 4; ++j) e[j] = elist[i + j];
      ushort4 u[4];
#pragma unroll
      for (int j = 0; j < 4; ++j)
        u[j] = *(const ushort4*)&xwh[(size_t)e[j].x * 64 + 4 * q];
#pragma unroll
      for (int j = 0; j < 4; ++j) {
        float w = __int_as_float(e[j].y);
        acc.x += relu_f(w * bf2f(u[j].x) + mbq.x);
        acc.y += relu_f(w * bf2f(u[j].y) + mbq.y);
        acc.z += relu_f(w * bf2f(u[j].z) + mbq.z);
        acc.w += relu_f(w * bf2f(u[j].w) + mbq.w);
      }
      i += 4;
    }
    for (; i < end; ++i) {
      int2 e0 = elist[i];
      ushort4 u0 = *(const ushort4*)&xwh[(size_t)e0.x * 64 + 4 * q];
      float w0 = __int_as_float(e0.y);
      acc.x += relu_f(w0 * bf2f(u0.x) + mbq.x);
      acc.y += relu_f(w0 * bf2f(u0.y) + mbq.y);
      acc.z += relu_f(w0 * bf2f(u0.z) + mbq.z);
      acc.w += relu_f(w0 * bf2f(u0.w) + mbq.w);
    }
    const float inv = 1.0f / fmaxf((float)c, 1.0f);
    acc.x *= inv; acc.y *= inv; acc.z *= inv; acc.w *= inv;
  }
  *(float4*)&s_rh[node_l][4 * q] = acc;
  __syncthreads();
  float4 o = make_float4(0.f, 0.f, 0.f, 0.f);
  for (int f = 0; f < 64; ++f) {
    float rv = s_rh[node_l][f];
    float4 wv = *(const float4*)&s_nk[f][4 * q];
    o.x += rv * wv.x; o.y += rv * wv.y; o.z += rv * wv.z; o.w += rv * wv.w;
  }
  if (n < n_nodes) {
    float4 bv = *(const float4*)&bias[4 * q];
    *(float4*)&out[(size_t)n * 128 + 4 * q] =
        make_float4(relu_f(o.x + bv.x), relu_f(o.y + bv.y),
                    relu_f(o.z + bv.z), relu_f(o.w + bv.w));
  }
}

// ===================== tier A kernels (packed-record, R11-verified) ==========
// FUSED hist16 + colscan16: each block computes its chunk-hist; the LAST block
// (device-scope done-counter handshake) performs the column scan and emits osub.
__global__ __launch_bounds__(256) void k_hist16_scan(
    const int* __restrict__ bpk, const int* __restrict__ bcur,
    int* __restrict__ hist, int* __restrict__ osub, int* __restrict__ done,
    int cap, int chunk, int sliceN)
{
  __shared__ int h[MAXSUB];
  __shared__ int part[256];
  __shared__ int s_last;
  const int s   = blockIdx.x & 7;
  const int blk = blockIdx.x >> 3;
  const int tid = threadIdx.x;
  const int nsub = (sliceN + 15) >> 4;
  for (int i = tid; i < nsub; i += 256) h[i] = 0;
  __syncthreads();
  const int n_s  = min(bcur[s], cap);
  const int lo_e = blk * chunk;
  const int hi_e = min(lo_e + chunk, n_s);
  const int base = s * cap;
  for (int i = lo_e + tid; i < hi_e; i += 256) {
    atomicAdd(&h[((unsigned)bpk[base + i]) >> 21], 1);
  }
  __syncthreads();
  int* hrow = hist + (size_t)(s * NBH + blk) * MAXSUB;
  for (int i = tid; i < nsub; i += 256) hrow[i] = h[i];
  // handshake: make hist writes visible, count arrivals
  __threadfence();
  __syncthreads();
  if (tid == 0) s_last = (atomicAdd(done, 1) == (int)gridDim.x - 1) ? 1 : 0;
  __syncthreads();
  if (!s_last) return;
  __threadfence();
  // last block: column-exclusive scan over NBH chunk rows per slice (in place),
  // then exclusive scan over subbucket totals; slice base from bcur.
  const int G = (nsub + 255) >> 8;   // <= 4 since MAXSUB <= 1024
  for (int sl = 0; sl < 8; ++sl) {
    int* hs = hist + (size_t)sl * NBH * MAXSUB;
    for (int i = tid; i < nsub; i += 256) {
      int acc = 0;
      for (int b2 = 0; b2 < NBH; ++b2) {
        int* p = hs + (size_t)b2 * MAXSUB + i;
        int v = *p; *p = acc; acc += v;
      }
      h[i] = acc;                    // reuse h as per-subbucket totals
    }
    __syncthreads();
    int vals[4]; int loc = 0;
#pragma unroll
    for (int j = 0; j < 4; ++j) {
      int i = tid * G + j;
      int v = (j < G && i < nsub) ? h[i] : 0;
      vals[j] = loc; loc += v;
    }
    part[tid] = loc;
    __syncthreads();
    for (int d = 1; d < 256; d <<= 1) {
      int t = (tid >= d) ? part[tid - d] : 0;
      __syncthreads();
      part[tid] += t;
      __syncthreads();
    }
    int segpre = (tid == 0) ? 0 : part[tid - 1];
    int sbase = 0;
    for (int b2 = 0; b2 < sl; ++b2) sbase += min(bcur[b2], cap);
#pragma unroll
    for (int j = 0; j < 4; ++j) {
      int i = tid * G + j;
      if (j < G && i < nsub) osub[sl * nsub + i] = sbase + segpre + vals[j];
    }
    if (sl == 7 && tid == 255) osub[8 * nsub] = sbase + part[255];
    __syncthreads();
  }
}

// place16 from packed records: cur[pk>>21]; elist = (col | (rloc&15)<<27, ew).
__global__ __launch_bounds__(256) void k_place16_pk(
    const int* __restrict__ bpk, const float* __restrict__ bew,
    const int* __restrict__ bcur, const int* __restrict__ hist,
    const int* __restrict__ off_sub, int2* __restrict__ elist,
    int cap, int chunk, int sliceN)
{
  __shared__ int cur[MAXSUB];
  const int s   = blockIdx.x & 7;
  const int blk = blockIdx.x >> 3;
  const int tid = threadIdx.x;
  const int nsub = (sliceN + 15) >> 4;
  const int* hrow = hist + (size_t)(s * NBH + blk) * MAXSUB;
  for (int i = tid; i < nsub; i += 256) cur[i] = off_sub[s * nsub + i] + hrow[i];
  __syncthreads();
  const int n_s  = min(bcur[s], cap);
  const int lo_e = blk * chunk;
  const int hi_e = min(lo_e + chunk, n_s);
  const int base = s * cap;
  for (int i = lo_e + tid; i < hi_e; i += 256) {
    unsigned pk = (unsigned)bpk[base + i];
    float w = bew[base + i];
    int p = atomicAdd(&cur[pk >> 21], 1);
    elist[p] = make_int2((int)((pk & 0x1FFFFu) | (((pk >> 17) & 15u) << 27)),
                         __float_as_int(w));
  }
}

// Fused with in-block sort (HW-verified R8/R10/R11/R12, 62-68 us). UNCHANGED.
__global__ __launch_bounds__(256) void k_fused_sub(
    const int* __restrict__ osub, const int2* __restrict__ elist,
    const unsigned short* __restrict__ xwh, const float* __restrict__ mb,
    const float* __restrict__ nk, const float* __restrict__ bias,
    float* __restrict__ out, int n_nodes, int sliceN)
{
  __shared__ float s_nk[64][64];
  __shared__ float s_rh[16][68];
  __shared__ int s_h[16];
  __shared__ int s_pre[17];
  __shared__ int s_cur[16];
  __shared__ unsigned short s_idx[IDXCAP];
  const int tid = threadIdx.x;
  for (int i = tid; i < 1024; i += 256) {
    *(float4*)&s_nk[0][4 * i] = *(const float4*)&nk[4 * i];
  }
  const int s   = blockIdx.x & 7;
  const int sub = blockIdx.x >> 3;
  const int nsub = (sliceN + 15) >> 4;
  const int e0 = osub[s * nsub + sub];
  const int e1 = osub[s * nsub + sub + 1];
  const int g = tid >> 4;
  const int q = tid & 15;
  const float4 mbq = *(const float4*)&mb[4 * q];
  float4 acc = make_float4(0.f, 0.f, 0.f, 0.f);
  int cnt_g = 0;
  for (int c0 = e0; c0 < e1; c0 += IDXCAP) {
    const int m = min(IDXCAP, e1 - c0);
    if (tid < 16) s_h[tid] = 0;
    __syncthreads();
    for (int i = tid; i < m; i += 256) {
      atomicAdd(&s_h[((unsigned)elist[c0 + i].x) >> 27], 1);
    }
    __syncthreads();
    if (tid == 0) {
      int a = 0;
#pragma unroll
      for (int b = 0; b < 16; ++b) { s_pre[b] = a; s_cur[b] = a; a += s_h[b]; }
      s_pre[16] = a;
    }
    __syncthreads();
    for (int i = tid; i < m; i += 256) {
      int rl = ((unsigned)elist[c0 + i].x) >> 27;
      int p = atomicAdd(&s_cur[rl], 1);
      s_idx[p] = (unsigned short)i;
    }
    __syncthreads();
    const int st = s_pre[g];
    const int cN = s_h[g];
    cnt_g += cN;
    int k = 0;
    for (; k + 8 <= cN; k += 8) {
      int2 e[8];
#pragma unroll
      for (int j = 0; j < 8; ++j) e[j] = elist[c0 + s_idx[st + k + j]];
      ushort4 u[8];
#pragma unroll
      for (int j = 0; j < 8; ++j)
        u[j] = *(const ushort4*)&xwh[(size_t)(e[j].x & 0x07FFFFFF) * 64 + 4 * q];
#pragma unroll
      for (int j = 0; j < 8; ++j) {
        float w = __int_as_float(e[j].y);
        acc.x += relu_f(w * bf2f(u[j].x) + mbq.x);
        acc.y += relu_f(w * bf2f(u[j].y) + mbq.y);
        acc.z += relu_f(w * bf2f(u[j].z) + mbq.z);
        acc.w += relu_f(w * bf2f(u[j].w) + mbq.w);
      }
    }
    if (k + 4 <= cN) {
      int2 e[4];
#pragma unroll
      for (int j = 0; j < 4; ++j) e[j] = elist[c0 + s_idx[st + k + j]];
      ushort4 u[4];
#pragma unroll
      for (int j = 0; j < 4; ++j)
        u[j] = *(const ushort4*)&xwh[(size_t)(e[j].x & 0x07FFFFFF) * 64 + 4 * q];
#pragma unroll
      for (int j = 0; j < 4; ++j) {
        float w = __int_as_float(e[j].y);
        acc.x += relu_f(w * bf2f(u[j].x) + mbq.x);
        acc.y += relu_f(w * bf2f(u[j].y) + mbq.y);
        acc.z += relu_f(w * bf2f(u[j].z) + mbq.z);
        acc.w += relu_f(w * bf2f(u[j].w) + mbq.w);
      }
      k += 4;
    }
    for (; k < cN; ++k) {
      int2 ev = elist[c0 + s_idx[st + k]];
      ushort4 u0 = *(const ushort4*)&xwh[(size_t)(ev.x & 0x07FFFFFF) * 64 + 4 * q];
      float w = __int_as_float(ev.y);
      acc.x += relu_f(w * bf2f(u0.x) + mbq.x);
      acc.y += relu_f(w * bf2f(u0.y) + mbq.y);
      acc.z += relu_f(w * bf2f(u0.z) + mbq.z);
      acc.w += relu_f(w * bf2f(u0.w) + mbq.w);
    }
    __syncthreads();
  }
  const float inv = 1.0f / fmaxf((float)cnt_g, 1.0f);
  acc.x *= inv; acc.y *= inv; acc.z *= inv; acc.w *= inv;
  *(float4*)&s_rh[g][4 * q] = acc;
  __syncthreads();
  float4 o = make_float4(0.f, 0.f, 0.f, 0.f);
  for (int f = 0; f < 64; ++f) {
    float rv = s_rh[g][f];
    float4 wv = *(const float4*)&s_nk[f][4 * q];
    o.x += rv * wv.x; o.y += rv * wv.y; o.z += rv * wv.z; o.w += rv * wv.w;
  }
  const int loc = sub * 16 + g;
  const int n = s * sliceN + loc;
  if (loc < sliceN && n < n_nodes) {
    float4 bv = *(const float4*)&bias[4 * q];
    *(float4*)&out[(size_t)n * 128 + 4 * q] =
        make_float4(relu_f(o.x + bv.x), relu_f(o.y + bv.y),
                    relu_f(o.z + bv.z), relu_f(o.w + bv.w));
  }
}

extern "C" void kernel_launch(void* const* d_in, const int* in_sizes, int n_in,
                              void* d_out, int out_size, void* d_ws, size_t ws_size,
                              hipStream_t stream) {
  const float* x    = (const float*)d_in[0];
  const int*   ei   = (const int*)d_in[1];     // [2, E]
  const float* ew   = (const float*)d_in[2];
  const float* mk   = (const float*)d_in[3];
  const float* mb   = (const float*)d_in[4];
  const float* nk   = (const float*)d_in[5];
  const float* sk   = (const float*)d_in[6];
  const float* bias = (const float*)d_in[7];
  float* out = (float*)d_out;

  const int n_nodes = in_sizes[0] / 64;
  const int n_edges = in_sizes[2];
  const int* row = ei;
  const int* col = ei + n_edges;

  // ws layout: xwh | cnt | bcur(8) | off | bsum(128) | osub | elist | brow | bpair | hist
  unsigned short* xwh = (unsigned short*)d_ws;              // [N*64] bf16
  int*  cnt  = (int*)(xwh + (size_t)n_nodes * 64);
  int*  bcur = cnt + n_nodes;
  int*  off  = bcur + 8;                                    // tier A: off[0] = done
  int*  bsum = off + n_nodes;
  int*  osub = bsum + 128;                                  // [8*MAXSUB+8]
  size_t ebytes = ((size_t)((char*)(osub + 8 * MAXSUB + 8) - (char*)d_ws) + 7) & ~(size_t)7;
  int2* elist = (int2*)((char*)d_ws + ebytes);              // [E]
  const int cap = (n_edges >> 3) + 8192;                    // per-bucket capacity
  int*  brow  = (int*)(elist + n_edges);                    // [8*cap]; tier A: bpk
  size_t pboff = (((size_t)((char*)(brow + (size_t)8 * cap) - (char*)d_ws)) + 7) & ~(size_t)7;
  int2* bpair = (int2*)((char*)d_ws + pboff);               // [8*cap]; tier A: bew
  int*   bpk  = brow;
  float* bew  = (float*)bpair;
  size_t need_b = (size_t)((char*)(bpair + (size_t)8 * cap) - (char*)d_ws);
  size_t hoff = (need_b + 15) & ~(size_t)15;
  int*  hist  = (int*)((char*)d_ws + hoff);                 // [8*NBH*MAXSLICE]
  size_t need_a = hoff + (size_t)8 * NBH * MAXSLICE * sizeof(int);

  const int nb_scan = (n_nodes + 1023) / 1024;
  const int sliceN = (n_nodes + 7) >> 3;
  const int nsub = (sliceN + 15) >> 4;
  const int nbn = (n_nodes + 63) / 64;
  const int nbf = (n_nodes + 15) / 16;
  const int chunk = (cap + NBH - 1) / NBH;

  const bool fitsA = (ws_size >= need_a) && (sliceN <= MAXSLICE);
  const bool subOK = fitsA && (nsub <= MAXSUB) && (n_nodes >= 16) &&
                     (n_nodes < (1 << 17)) &&               // packed pk = col | rloc<<17
                     ((size_t)8 * cap >= (size_t)n_edges);

  if (subOK) {
    // tier A (R11 structure + fused hist/scan): memset(bcur+done) ->
    // [gemm ∥ bin packed] -> hist16+scan -> place16 -> fused_sub
    hipMemsetAsync(bcur, 0, 9 * sizeof(int), stream);   // bcur[0..7] + off[0]=done
    int nbb = (n_edges + 1023) / 1024;
    if (nbb > 2048) nbb = 2048;
    if (nbb < 1) nbb = 1;
    k_gemm_bin<<<nbn + nbb, 256, 0, stream>>>(x, mk, sk, bias, xwh, out, n_nodes,
                                              row, col, ew, bpk, bew, bcur,
                                              n_edges, sliceN, cap, nbn);
    k_hist16_scan<<<8 * NBH, 256, 0, stream>>>(bpk, bcur, hist, osub, off,
                                               cap, chunk, sliceN);
    k_place16_pk<<<8 * NBH, 256, 0, stream>>>(bpk, bew, bcur, hist, osub,
                                              elist, cap, chunk, sliceN);
    k_fused_sub<<<8 * nsub, 256, 0, stream>>>(osub, elist, xwh, mb, nk, bias,
                                              out, n_nodes, sliceN);
  } else if (fitsA) {
    // tier B: node-level CSR (proven R3 path)
    hipMemsetAsync(bcur, 0, 8 * sizeof(int), stream);
    k_node_dual_gemm<<<nbn, 256, 0, stream>>>(x, mk, sk, bias, xwh, out, n_nodes);
    int nbb = (n_edges + 1023) / 1024;
    if (nbb > 2048) nbb = 2048;
    k_bin<<<nbb, 256, 0, stream>>>(row, col, ew, brow, bpair, bcur,
                                   n_edges, sliceN, cap);
    k_hist<<<8 * NBH, 256, 0, stream>>>(brow, bcur, hist, cap, chunk, sliceN);
    const int ncb = (sliceN + 1023) / 1024;
    k_colscan<<<8 * ncb, 256, 0, stream>>>(hist, cnt, sliceN, n_nodes);
    k_bsum<<<nb_scan, 1024, 0, stream>>>(cnt, bsum, n_nodes);
    k_boffs<<<nb_scan, 1024, 0, stream>>>(cnt, bsum, off, n_nodes, nb_scan);
    k_place<<<8 * NBH, 256, 0, stream>>>(brow, bpair, bcur, hist, off,
                                         elist, cap, chunk, sliceN, n_nodes);
    k_fused_csr<<<nbf, 256, 0, stream>>>(cnt, off, elist, xwh, mb, nk,
                                         bias, out, n_nodes, 1);
  } else {
    // tier C: original verified path
    hipMemsetAsync(cnt, 0, (size_t)n_nodes * sizeof(int), stream);
    k_node_dual_gemm<<<nbn, 256, 0, stream>>>(x, mk, sk, bias, xwh, out, n_nodes);
    const int nbe = (n_edges + 255) / 256;
    k_count<<<nbe, 256, 0, stream>>>(row, cnt, n_edges);
    k_bsum<<<nb_scan, 1024, 0, stream>>>(cnt, bsum, n_nodes);
    k_boffs<<<nb_scan, 1024, 0, stream>>>(cnt, bsum, off, n_nodes, nb_scan);
    k_build_sliced<<<1024, 256, 0, stream>>>(row, col, ew, off, elist,
                                             n_edges, n_nodes);
    k_fused_csr<<<nbf, 256, 0, stream>>>(cnt, off, elist, xwh, mb, nk,
                                         bias, out, n_nodes, 0);
  }
}

// Round 14
// 234.447 us; speedup vs baseline: 1.3852x; 1.3852x over previous
//
#include <hip/hip_runtime.h>

#define MAXSLICE 12544   // max nodes per slice (node-level tier-B path)
#define MAXSUB   800     // max 16-node subbuckets per slice (>= 12544/16)
#define NBH 32           // histogram/place chunks per slice
#define IDXCAP 512       // per-chunk in-fused sort capacity

static __device__ __forceinline__ float relu_f(float v) { return fmaxf(v, 0.f); }

// fp32 -> bf16 with round-to-nearest-even
static __device__ __forceinline__ unsigned short f2bf(float f) {
  unsigned u = __float_as_uint(f);
  u += 0x7fffu + ((u >> 16) & 1u);
  return (unsigned short)(u >> 16);
}
static __device__ __forceinline__ float bf2f(unsigned short h) {
  return __uint_as_float(((unsigned)h) << 16);
}

// ===== Mega-kernel (tier A, HW-verified R11 @236.9 us): blocks < nbn do GEMM;
// rest do packed bin. pk = col | rloc<<17 (n_nodes < 2^17), ew planar. =====
__global__ __launch_bounds__(256) void k_gemm_bin(
    const float* __restrict__ x, const float* __restrict__ mk,
    const float* __restrict__ sk, const float* __restrict__ bias,
    unsigned short* __restrict__ xwh, float* __restrict__ out, int n_nodes,
    const int* __restrict__ row, const int* __restrict__ col,
    const float* __restrict__ ew,
    int* __restrict__ bpk, float* __restrict__ bew, int* __restrict__ bcur,
    int n_edges, int sliceN, int cap, int nbn)
{
  __shared__ union U {
    struct { float mks[64][64]; float sks[64][64]; float xT[64][68]; } g;
    struct { int wcnt[4][8]; int tot[8]; int toff[8]; int gaddr[8];
             int pk[1024]; float ww[1024]; } b;
  } u;
  const int tid = threadIdx.x;

  if (blockIdx.x < nbn) {
    // ---- GEMM path ----
    for (int i = tid; i < 4096; i += 256) {
      u.g.mks[i >> 6][i & 63] = mk[i];
      u.g.sks[i >> 6][i & 63] = sk[i];
    }
    const int node0 = blockIdx.x * 64;
    for (int i = tid; i < 4096; i += 256) {
      int nl = i >> 6, f = i & 63;
      int n = node0 + nl;
      u.g.xT[f][nl] = (n < n_nodes) ? x[(size_t)n * 64 + f] : 0.f;
    }
    __syncthreads();
    const int g  = tid >> 4;
    const int ub = (tid & 15) * 4;
    float am[4][4] = {{0.f}};
    float as[4][4] = {{0.f}};
    for (int f = 0; f < 64; ++f) {
      float4 wm = *(const float4*)&u.g.mks[f][ub];
      float4 ws = *(const float4*)&u.g.sks[f][ub];
      float4 xv = *(const float4*)&u.g.xT[f][4 * g];
      const float xs[4] = {xv.x, xv.y, xv.z, xv.w};
#pragma unroll
      for (int j = 0; j < 4; ++j) {
        am[j][0] += xs[j] * wm.x; am[j][1] += xs[j] * wm.y;
        am[j][2] += xs[j] * wm.z; am[j][3] += xs[j] * wm.w;
        as[j][0] += xs[j] * ws.x; as[j][1] += xs[j] * ws.y;
        as[j][2] += xs[j] * ws.z; as[j][3] += xs[j] * ws.w;
      }
    }
    float4 bv = *(const float4*)&bias[64 + ub];
#pragma unroll
    for (int j = 0; j < 4; ++j) {
      int n = node0 + 4 * g + j;
      if (n >= n_nodes) break;
      ushort4 o1 = make_ushort4(f2bf(am[j][0]), f2bf(am[j][1]),
                                f2bf(am[j][2]), f2bf(am[j][3]));
      *(ushort4*)&xwh[(size_t)n * 64 + ub] = o1;
      *(float4*)&out[(size_t)n * 128 + 64 + ub] =
          make_float4(relu_f(as[j][0] + bv.x), relu_f(as[j][1] + bv.y),
                      relu_f(as[j][2] + bv.z), relu_f(as[j][3] + bv.w));
    }
    return;
  }

  // ---- BIN path (packed records) ----
  const int vbid = blockIdx.x - nbn;
  const int nvb  = gridDim.x - nbn;
  const int wave = tid >> 6;
  const int lane = tid & 63;
  const unsigned usliceN = (unsigned)sliceN;
  const int stride = nvb * 1024;
  for (int e0 = vbid * 1024; e0 < n_edges; e0 += stride) {
    const int e = e0 + 4 * tid;
    int   pp[4];
    float ww[4];
    int   ss[4];
    if (e + 3 < n_edges) {
      int4 r4   = *(const int4*)&row[e];
      int4 c4   = *(const int4*)&col[e];
      float4 w4 = *(const float4*)&ew[e];
      int rr[4] = {r4.x, r4.y, r4.z, r4.w};
      int cc[4] = {c4.x, c4.y, c4.z, c4.w};
      ww[0] = w4.x; ww[1] = w4.y; ww[2] = w4.z; ww[3] = w4.w;
#pragma unroll
      for (int j = 0; j < 4; ++j) {
        ss[j] = (int)((unsigned)rr[j] / usliceN);
        pp[j] = cc[j] | ((rr[j] - ss[j] * sliceN) << 17);
      }
    } else {
#pragma unroll
      for (int j = 0; j < 4; ++j) {
        int ej = e + j;
        bool v = ej < n_edges;
        int r = v ? row[ej] : 0;
        int c = v ? col[ej] : 0;
        ww[j] = v ? ew[ej] : 0.f;
        ss[j] = v ? (int)((unsigned)r / usliceN) : -1;
        pp[j] = v ? (c | ((r - ss[j] * sliceN) << 17)) : 0;
      }
    }
#pragma unroll
    for (int b = 0; b < 8; ++b) {
      int c = 0;
#pragma unroll
      for (int j = 0; j < 4; ++j) c += __popcll(__ballot(ss[j] == b));
      if (lane == 0) u.b.wcnt[wave][b] = c;
    }
    __syncthreads();
    if (wave == 0 && lane < 8) {
      const int b = lane;
      int t0 = u.b.wcnt[0][b], t1 = u.b.wcnt[1][b];
      int t2 = u.b.wcnt[2][b], t3 = u.b.wcnt[3][b];
      int tot = t0 + t1 + t2 + t3;
      u.b.tot[b] = tot;
      u.b.wcnt[0][b] = 0;
      u.b.wcnt[1][b] = t0;
      u.b.wcnt[2][b] = t0 + t1;
      u.b.wcnt[3][b] = t0 + t1 + t2;
      int gbase = tot ? atomicAdd(&bcur[b], tot) : 0;
      int pre = 0;
#pragma unroll
      for (int j2 = 0; j2 < 8; ++j2) pre += (j2 < b) ? u.b.tot[j2] : 0;
      u.b.toff[b]  = pre;
      u.b.gaddr[b] = b * cap + gbase - pre;
    }
    __syncthreads();
#pragma unroll
    for (int b = 0; b < 8; ++b) {
      const int sb = u.b.toff[b] + u.b.wcnt[wave][b];
      int off_local = 0;
#pragma unroll
      for (int j = 0; j < 4; ++j) {
        unsigned long long mm = __ballot(ss[j] == b);
        if (ss[j] == b) {
          int rank = __popcll(mm & ((1ull << lane) - 1ull));
          int slot = sb + off_local + rank;
          u.b.pk[slot] = pp[j];
          u.b.ww[slot] = ww[j];
        }
        off_local += __popcll(mm);
      }
    }
    __syncthreads();
    const int total = u.b.toff[7] + u.b.tot[7];
    for (int i2 = tid; i2 < total; i2 += 256) {
      int b = 0;
#pragma unroll
      for (int j2 = 1; j2 < 8; ++j2) b += (i2 >= u.b.toff[j2]) ? 1 : 0;
      int a = u.b.gaddr[b] + i2;
      if (a < (b + 1) * cap) {
        bpk[a] = u.b.pk[i2];
        bew[a] = u.b.ww[i2];
      }
    }
    __syncthreads();
  }
}

// Standalone GEMM (tiers B/C)
__global__ __launch_bounds__(256) void k_node_dual_gemm(
    const float* __restrict__ x, const float* __restrict__ mk,
    const float* __restrict__ sk, const float* __restrict__ bias,
    unsigned short* __restrict__ xwh, float* __restrict__ out, int n_nodes)
{
  __shared__ float s_mk[64][64];
  __shared__ float s_sk[64][64];
  __shared__ float s_xT[64][68];
  const int tid = threadIdx.x;
  for (int i = tid; i < 4096; i += 256) {
    s_mk[i >> 6][i & 63] = mk[i];
    s_sk[i >> 6][i & 63] = sk[i];
  }
  const int node0 = blockIdx.x * 64;
  for (int i = tid; i < 4096; i += 256) {
    int nl = i >> 6, f = i & 63;
    int n = node0 + nl;
    s_xT[f][nl] = (n < n_nodes) ? x[(size_t)n * 64 + f] : 0.f;
  }
  __syncthreads();
  const int g  = tid >> 4;
  const int ub = (tid & 15) * 4;
  float am[4][4] = {{0.f}};
  float as[4][4] = {{0.f}};
  for (int f = 0; f < 64; ++f) {
    float4 wm = *(const float4*)&s_mk[f][ub];
    float4 ws = *(const float4*)&s_sk[f][ub];
    float4 xv = *(const float4*)&s_xT[f][4 * g];
    const float xs[4] = {xv.x, xv.y, xv.z, xv.w};
#pragma unroll
    for (int j = 0; j < 4; ++j) {
      am[j][0] += xs[j] * wm.x; am[j][1] += xs[j] * wm.y;
      am[j][2] += xs[j] * wm.z; am[j][3] += xs[j] * wm.w;
      as[j][0] += xs[j] * ws.x; as[j][1] += xs[j] * ws.y;
      as[j][2] += xs[j] * ws.z; as[j][3] += xs[j] * ws.w;
    }
  }
  float4 bv = *(const float4*)&bias[64 + ub];
#pragma unroll
  for (int j = 0; j < 4; ++j) {
    int n = node0 + 4 * g + j;
    if (n >= n_nodes) break;
    ushort4 o1 = make_ushort4(f2bf(am[j][0]), f2bf(am[j][1]),
                              f2bf(am[j][2]), f2bf(am[j][3]));
    *(ushort4*)&xwh[(size_t)n * 64 + ub] = o1;
    *(float4*)&out[(size_t)n * 128 + 64 + ub] =
        make_float4(relu_f(as[j][0] + bv.x), relu_f(as[j][1] + bv.y),
                    relu_f(as[j][2] + bv.z), relu_f(as[j][3] + bv.w));
  }
}

// ---------- tier C (original path) ----------
__global__ __launch_bounds__(256) void k_count(
    const int* __restrict__ row, int* __restrict__ cnt, int n_edges)
{
  int e = blockIdx.x * 256 + threadIdx.x;
  if (e < n_edges) atomicAdd(&cnt[row[e]], 1);
}

__global__ __launch_bounds__(256) void k_build_sliced(
    const int* __restrict__ row, const int* __restrict__ col,
    const float* __restrict__ ew, int* __restrict__ off,
    int2* __restrict__ elist, int n_edges, int n_nodes)
{
  const int slice = blockIdx.x & 7;
  const int vb    = blockIdx.x >> 3;
  const int nvb   = gridDim.x >> 3;
  const int sliceN = (n_nodes + 7) >> 3;
  const int lo = slice * sliceN;
  const int hi = min(lo + sliceN, n_nodes);
  for (int e = vb * 256 + threadIdx.x; e < n_edges; e += nvb * 256) {
    int r = row[e];
    if (r >= lo && r < hi) {
      int pos = atomicAdd(&off[r], 1);
      elist[pos] = make_int2(col[e], __float_as_int(ew[e]));
    }
  }
}
// ---------- end tier C ----------

// Scan step 1: per-1024-block sums of cnt.
__global__ __launch_bounds__(1024) void k_bsum(
    const int* __restrict__ cnt, int* __restrict__ bsum, int n)
{
  __shared__ int s[1024];
  int tid = threadIdx.x;
  int i = blockIdx.x * 1024 + tid;
  s[tid] = (i < n) ? cnt[i] : 0;
  __syncthreads();
  for (int d = 512; d > 0; d >>= 1) {
    if (tid < d) s[tid] += s[tid + d];
    __syncthreads();
  }
  if (tid == 0) bsum[blockIdx.x] = s[0];
}

// Scan step 2: block-local exclusive scan of cnt + block prefix from bsum.
__global__ __launch_bounds__(1024) void k_boffs(
    const int* __restrict__ cnt, const int* __restrict__ bsum,
    int* __restrict__ off, int n, int nb)
{
  __shared__ int s[1024];
  __shared__ int sp[128];
  int tid = threadIdx.x;
  if (tid < 128) {
    int acc = 0;
    for (int j = tid; j < blockIdx.x && j < nb; j += 128) acc += bsum[j];
    sp[tid] = acc;
  }
  int i = blockIdx.x * 1024 + tid;
  int v = (i < n) ? cnt[i] : 0;
  s[tid] = v;
  __syncthreads();
  for (int d = 64; d > 0; d >>= 1) {
    if (tid < d) sp[tid] += sp[tid + d];
    __syncthreads();
  }
  for (int d = 1; d < 1024; d <<= 1) {
    int t = (tid >= d) ? s[tid - d] : 0;
    __syncthreads();
    s[tid] += t;
    __syncthreads();
  }
  if (i < n) off[i] = s[tid] - v + sp[0];
}

// Pass B (tier B, full records): [HW-verified R6/R7/R8]
__global__ __launch_bounds__(256) void k_bin(
    const int* __restrict__ row, const int* __restrict__ col,
    const float* __restrict__ ew,
    int* __restrict__ brow, int2* __restrict__ bpair,
    int* __restrict__ bcur, int n_edges, int sliceN, int cap)
{
  __shared__ int  s_wcnt[4][8];
  __shared__ int  s_tot[8];
  __shared__ int  s_toff[8];
  __shared__ int  s_gaddr[8];
  __shared__ int  s_rowst[1024];
  __shared__ int2 s_pairst[1024];
  const int tid  = threadIdx.x;
  const int wave = tid >> 6;
  const int lane = tid & 63;
  const unsigned usliceN = (unsigned)sliceN;
  const int stride = gridDim.x * 1024;
  for (int e0 = blockIdx.x * 1024; e0 < n_edges; e0 += stride) {
    const int e = e0 + 4 * tid;
    int   rr[4], cc[4];
    float ww[4];
    int   ss[4];
    if (e + 3 < n_edges) {
      int4 r4   = *(const int4*)&row[e];
      int4 c4   = *(const int4*)&col[e];
      float4 w4 = *(const float4*)&ew[e];
      rr[0] = r4.x; rr[1] = r4.y; rr[2] = r4.z; rr[3] = r4.w;
      cc[0] = c4.x; cc[1] = c4.y; cc[2] = c4.z; cc[3] = c4.w;
      ww[0] = w4.x; ww[1] = w4.y; ww[2] = w4.z; ww[3] = w4.w;
#pragma unroll
      for (int j = 0; j < 4; ++j) ss[j] = (int)((unsigned)rr[j] / usliceN);
    } else {
#pragma unroll
      for (int j = 0; j < 4; ++j) {
        int ej = e + j;
        bool v = ej < n_edges;
        rr[j] = v ? row[ej] : 0;
        cc[j] = v ? col[ej] : 0;
        ww[j] = v ? ew[ej]  : 0.f;
        ss[j] = v ? (int)((unsigned)rr[j] / usliceN) : -1;
      }
    }
#pragma unroll
    for (int b = 0; b < 8; ++b) {
      int c = 0;
#pragma unroll
      for (int j = 0; j < 4; ++j) c += __popcll(__ballot(ss[j] == b));
      if (lane == 0) s_wcnt[wave][b] = c;
    }
    __syncthreads();
    if (wave == 0 && lane < 8) {
      const int b = lane;
      int t0 = s_wcnt[0][b], t1 = s_wcnt[1][b], t2 = s_wcnt[2][b], t3 = s_wcnt[3][b];
      int tot = t0 + t1 + t2 + t3;
      s_tot[b] = tot;
      s_wcnt[0][b] = 0;
      s_wcnt[1][b] = t0;
      s_wcnt[2][b] = t0 + t1;
      s_wcnt[3][b] = t0 + t1 + t2;
      int gbase = tot ? atomicAdd(&bcur[b], tot) : 0;
      int pre = 0;
#pragma unroll
      for (int j2 = 0; j2 < 8; ++j2) pre += (j2 < b) ? s_tot[j2] : 0;
      s_toff[b]  = pre;
      s_gaddr[b] = b * cap + gbase - pre;
    }
    __syncthreads();
#pragma unroll
    for (int b = 0; b < 8; ++b) {
      const int sb = s_toff[b] + s_wcnt[wave][b];
      int off_local = 0;
#pragma unroll
      for (int j = 0; j < 4; ++j) {
        unsigned long long mm = __ballot(ss[j] == b);
        if (ss[j] == b) {
          int rank = __popcll(mm & ((1ull << lane) - 1ull));
          int slot = sb + off_local + rank;
          s_rowst[slot]  = rr[j];
          s_pairst[slot] = make_int2(cc[j], __float_as_int(ww[j]));
        }
        off_local += __popcll(mm);
      }
    }
    __syncthreads();
    const int total = s_toff[7] + s_tot[7];
    for (int i2 = tid; i2 < total; i2 += 256) {
      int b = 0;
#pragma unroll
      for (int j2 = 1; j2 < 8; ++j2) b += (i2 >= s_toff[j2]) ? 1 : 0;
      int a = s_gaddr[b] + i2;
      if (a < (b + 1) * cap) {
        brow[a]  = s_rowst[i2];
        bpair[a] = s_pairst[i2];
      }
    }
    __syncthreads();
  }
}

// ===================== tier B (node-level CSR, proven R3 path) =====================
__global__ __launch_bounds__(256) void k_hist(
    const int* __restrict__ brow, const int* __restrict__ bcur,
    int* __restrict__ hist, int cap, int chunk, int sliceN)
{
  __shared__ int h[MAXSLICE];
  const int s   = blockIdx.x & 7;
  const int blk = blockIdx.x >> 3;
  const int tid = threadIdx.x;
  for (int i = tid; i < MAXSLICE; i += 256) h[i] = 0;
  __syncthreads();
  const int n_s  = min(bcur[s], cap);
  const int lo_e = blk * chunk;
  const int hi_e = min(lo_e + chunk, n_s);
  const int base = s * cap;
  const int lo   = s * sliceN;
  for (int i = lo_e + tid; i < hi_e; i += 256) {
    atomicAdd(&h[brow[base + i] - lo], 1);
  }
  __syncthreads();
  int* hrow = hist + (size_t)(s * NBH + blk) * MAXSLICE;
  for (int i = tid; i < MAXSLICE / 4; i += 256) {
    ((int4*)hrow)[i] = ((const int4*)h)[i];
  }
}

__global__ __launch_bounds__(256) void k_colscan(
    int* __restrict__ hist, int* __restrict__ cnt, int sliceN, int n_nodes)
{
  const int s  = blockIdx.x & 7;
  const int cb = blockIdx.x >> 3;
  const int b0 = cb * 1024 + threadIdx.x * 4;
  if (b0 >= sliceN) return;
  int4 acc = make_int4(0, 0, 0, 0);
  int* hs = hist + (size_t)s * NBH * MAXSLICE;
#pragma unroll 4
  for (int blk = 0; blk < NBH; ++blk) {
    int4* p = (int4*)(hs + (size_t)blk * MAXSLICE + b0);
    int4 v = *p;
    *p = acc;
    acc.x += v.x; acc.y += v.y; acc.z += v.z; acc.w += v.w;
  }
  const int node = s * sliceN + b0;
  if (b0 + 3 < sliceN && node + 3 < n_nodes) {
    *(int4*)&cnt[node] = acc;
  } else {
    int a[4] = {acc.x, acc.y, acc.z, acc.w};
    for (int j = 0; j < 4; ++j)
      if (b0 + j < sliceN && node + j < n_nodes) cnt[node + j] = a[j];
  }
}

__global__ __launch_bounds__(256) void k_place(
    const int* __restrict__ brow, const int2* __restrict__ bpair,
    const int* __restrict__ bcur, const int* __restrict__ hist,
    const int* __restrict__ off, int2* __restrict__ elist,
    int cap, int chunk, int sliceN, int n_nodes)
{
  __shared__ int cur[MAXSLICE];
  const int s   = blockIdx.x & 7;
  const int blk = blockIdx.x >> 3;
  const int tid = threadIdx.x;
  const int lo  = s * sliceN;
  const int hi  = min(lo + sliceN, n_nodes);
  const int nb  = hi - lo;
  const int* hrow = hist + (size_t)(s * NBH + blk) * MAXSLICE;
  for (int i = tid; i < nb; i += 256) cur[i] = off[lo + i] + hrow[i];
  __syncthreads();
  const int n_s  = min(bcur[s], cap);
  const int lo_e = blk * chunk;
  const int hi_e = min(lo_e + chunk, n_s);
  const int base = s * cap;
  for (int i = lo_e + tid; i < hi_e; i += 256) {
    int r = brow[base + i] - lo;
    int p = atomicAdd(&cur[r], 1);
    elist[p] = bpair[base + i];
  }
}

// R3's proven fused kernel (tier B/C): per-node 16-lane groups, 8-deep unroll.
__global__ __launch_bounds__(256) void k_fused_csr(
    const int* __restrict__ cnt, const int* __restrict__ off,
    const int2* __restrict__ elist, const unsigned short* __restrict__ xwh,
    const float* __restrict__ mb, const float* __restrict__ nk,
    const float* __restrict__ bias, float* __restrict__ out, int n_nodes,
    int starts)
{
  __shared__ float s_nk[64][64];
  __shared__ float s_rh[16][68];
  const int tid = threadIdx.x;
  for (int i = tid; i < 1024; i += 256) {
    *(float4*)&s_nk[0][4 * i] = *(const float4*)&nk[4 * i];
  }
  const int node_l = tid >> 4;
  const int q = tid & 15;
  const int n = blockIdx.x * 16 + node_l;
  float4 acc = make_float4(0.f, 0.f, 0.f, 0.f);
  if (n < n_nodes) {
    const float4 mbq = *(const float4*)&mb[4 * q];
    const int c = cnt[n];
    int i = off[n] - (starts ? 0 : c);
    const int end = i + c;
    for (; i + 8 <= end; i += 8) {
      int2 e[8];
#pragma unroll
      for (int j = 0; j < 8; ++j) e[j] = elist[i + j];
      ushort4 u[8];
#pragma unroll
      for (int j = 0; j < 8; ++j)
        u[j] = *(const ushort4*)&xwh[(size_t)e[j].x * 64 + 4 * q];
#pragma unroll
      for (int j = 0; j < 8; ++j) {
        float w = __int_as_float(e[j].y);
        acc.x += relu_f(w * bf2f(u[j].x) + mbq.x);
        acc.y += relu_f(w * bf2f(u[j].y) + mbq.y);
        acc.z += relu_f(w * bf2f(u[j].z) + mbq.z);
        acc.w += relu_f(w * bf2f(u[j].w) + mbq.w);
      }
    }
    if (i + 4 <= end) {
      int2 e[4];
#pragma unroll
      for (int j = 0; j < 4; ++j) e[j] = elist[i + j];
      ushort4 u[4];
#pragma unroll
      for (int j = 0; j < 4; ++j)
        u[j] = *(const ushort4*)&xwh[(size_t)e[j].x * 64 + 4 * q];
#pragma unroll
      for (int j = 0; j < 4; ++j) {
        float w = __int_as_float(e[j].y);
        acc.x += relu_f(w * bf2f(u[j].x) + mbq.x);
        acc.y += relu_f(w * bf2f(u[j].y) + mbq.y);
        acc.z += relu_f(w * bf2f(u[j].z) + mbq.z);
        acc.w += relu_f(w * bf2f(u[j].w) + mbq.w);
      }
      i += 4;
    }
    for (; i < end; ++i) {
      int2 e0 = elist[i];
      ushort4 u0 = *(const ushort4*)&xwh[(size_t)e0.x * 64 + 4 * q];
      float w0 = __int_as_float(e0.y);
      acc.x += relu_f(w0 * bf2f(u0.x) + mbq.x);
      acc.y += relu_f(w0 * bf2f(u0.y) + mbq.y);
      acc.z += relu_f(w0 * bf2f(u0.z) + mbq.z);
      acc.w += relu_f(w0 * bf2f(u0.w) + mbq.w);
    }
    const float inv = 1.0f / fmaxf((float)c, 1.0f);
    acc.x *= inv; acc.y *= inv; acc.z *= inv; acc.w *= inv;
  }
  *(float4*)&s_rh[node_l][4 * q] = acc;
  __syncthreads();
  float4 o = make_float4(0.f, 0.f, 0.f, 0.f);
  for (int f = 0; f < 64; ++f) {
    float rv = s_rh[node_l][f];
    float4 wv = *(const float4*)&s_nk[f][4 * q];
    o.x += rv * wv.x; o.y += rv * wv.y; o.z += rv * wv.z; o.w += rv * wv.w;
  }
  if (n < n_nodes) {
    float4 bv = *(const float4*)&bias[4 * q];
    *(float4*)&out[(size_t)n * 128 + 4 * q] =
        make_float4(relu_f(o.x + bv.x), relu_f(o.y + bv.y),
                    relu_f(o.z + bv.z), relu_f(o.w + bv.w));
  }
}

// ===================== tier A kernels (packed-record, R11-verified) ==========
// hist over 16-node subbuckets from packed records: sub = pk>>21.
__global__ __launch_bounds__(256) void k_hist16_pk(
    const int* __restrict__ bpk, const int* __restrict__ bcur,
    int* __restrict__ hist, int cap, int chunk, int sliceN)
{
  __shared__ int h[MAXSUB];
  const int s   = blockIdx.x & 7;
  const int blk = blockIdx.x >> 3;
  const int tid = threadIdx.x;
  const int nsub = (sliceN + 15) >> 4;
  for (int i = tid; i < nsub; i += 256) h[i] = 0;
  __syncthreads();
  const int n_s  = min(bcur[s], cap);
  const int lo_e = blk * chunk;
  const int hi_e = min(lo_e + chunk, n_s);
  const int base = s * cap;
  for (int i = lo_e + tid; i < hi_e; i += 256) {
    atomicAdd(&h[((unsigned)bpk[base + i]) >> 21], 1);
  }
  __syncthreads();
  int* hrow = hist + (size_t)(s * NBH + blk) * MAXSUB;
  for (int i = tid; i < nsub; i += 256) hrow[i] = h[i];
}

// colscan16: [HW-verified R6/R7/R8/R11]
__global__ __launch_bounds__(1024) void k_colscan16(
    int* __restrict__ hist, const int* __restrict__ bcur,
    int* __restrict__ off_sub, int cap, int sliceN)
{
  __shared__ int s_t[1024];
  const int s = blockIdx.x;
  const int tid = threadIdx.x;
  const int nsub = (sliceN + 15) >> 4;
  int acc = 0;
  if (tid < nsub) {
    int* hs = hist + (size_t)s * NBH * MAXSUB;
    for (int blk = 0; blk < NBH; ++blk) {
      int* p = hs + (size_t)blk * MAXSUB + tid;
      int v = *p;
      *p = acc;
      acc += v;
    }
  }
  s_t[tid] = (tid < nsub) ? acc : 0;
  __syncthreads();
  for (int d = 1; d < 1024; d <<= 1) {
    int t = (tid >= d) ? s_t[tid - d] : 0;
    __syncthreads();
    s_t[tid] += t;
    __syncthreads();
  }
  int base = 0;
  for (int b = 0; b < s; ++b) base += min(bcur[b], cap);
  int excl = (tid == 0) ? 0 : s_t[tid - 1];
  if (tid < nsub) off_sub[s * nsub + tid] = base + excl;
  if (s == 7 && tid == 1023) off_sub[8 * nsub] = base + s_t[1023];
}

// place16 from packed records: cur[pk>>21]; elist = (col | (rloc&15)<<27, ew).
__global__ __launch_bounds__(256) void k_place16_pk(
    const int* __restrict__ bpk, const float* __restrict__ bew,
    const int* __restrict__ bcur, const int* __restrict__ hist,
    const int* __restrict__ off_sub, int2* __restrict__ elist,
    int cap, int chunk, int sliceN)
{
  __shared__ int cur[MAXSUB];
  const int s   = blockIdx.x & 7;
  const int blk = blockIdx.x >> 3;
  const int tid = threadIdx.x;
  const int nsub = (sliceN + 15) >> 4;
  const int* hrow = hist + (size_t)(s * NBH + blk) * MAXSUB;
  for (int i = tid; i < nsub; i += 256) cur[i] = off_sub[s * nsub + i] + hrow[i];
  __syncthreads();
  const int n_s  = min(bcur[s], cap);
  const int lo_e = blk * chunk;
  const int hi_e = min(lo_e + chunk, n_s);
  const int base = s * cap;
  for (int i = lo_e + tid; i < hi_e; i += 256) {
    unsigned pk = (unsigned)bpk[base + i];
    float w = bew[base + i];
    int p = atomicAdd(&cur[pk >> 21], 1);
    elist[p] = make_int2((int)((pk & 0x1FFFFu) | (((pk >> 17) & 15u) << 27)),
                         __float_as_int(w));
  }
}

// Fused with in-block sort (HW-verified R8/R10/R11/R12, 62-68 us). UNCHANGED.
__global__ __launch_bounds__(256) void k_fused_sub(
    const int* __restrict__ osub, const int2* __restrict__ elist,
    const unsigned short* __restrict__ xwh, const float* __restrict__ mb,
    const float* __restrict__ nk, const float* __restrict__ bias,
    float* __restrict__ out, int n_nodes, int sliceN)
{
  __shared__ float s_nk[64][64];
  __shared__ float s_rh[16][68];
  __shared__ int s_h[16];
  __shared__ int s_pre[17];
  __shared__ int s_cur[16];
  __shared__ unsigned short s_idx[IDXCAP];
  const int tid = threadIdx.x;
  for (int i = tid; i < 1024; i += 256) {
    *(float4*)&s_nk[0][4 * i] = *(const float4*)&nk[4 * i];
  }
  const int s   = blockIdx.x & 7;
  const int sub = blockIdx.x >> 3;
  const int nsub = (sliceN + 15) >> 4;
  const int e0 = osub[s * nsub + sub];
  const int e1 = osub[s * nsub + sub + 1];
  const int g = tid >> 4;
  const int q = tid & 15;
  const float4 mbq = *(const float4*)&mb[4 * q];
  float4 acc = make_float4(0.f, 0.f, 0.f, 0.f);
  int cnt_g = 0;
  for (int c0 = e0; c0 < e1; c0 += IDXCAP) {
    const int m = min(IDXCAP, e1 - c0);
    if (tid < 16) s_h[tid] = 0;
    __syncthreads();
    for (int i = tid; i < m; i += 256) {
      atomicAdd(&s_h[((unsigned)elist[c0 + i].x) >> 27], 1);
    }
    __syncthreads();
    if (tid == 0) {
      int a = 0;
#pragma unroll
      for (int b = 0; b < 16; ++b) { s_pre[b] = a; s_cur[b] = a; a += s_h[b]; }
      s_pre[16] = a;
    }
    __syncthreads();
    for (int i = tid; i < m; i += 256) {
      int rl = ((unsigned)elist[c0 + i].x) >> 27;
      int p = atomicAdd(&s_cur[rl], 1);
      s_idx[p] = (unsigned short)i;
    }
    __syncthreads();
    const int st = s_pre[g];
    const int cN = s_h[g];
    cnt_g += cN;
    int k = 0;
    for (; k + 8 <= cN; k += 8) {
      int2 e[8];
#pragma unroll
      for (int j = 0; j < 8; ++j) e[j] = elist[c0 + s_idx[st + k + j]];
      ushort4 u[8];
#pragma unroll
      for (int j = 0; j < 8; ++j)
        u[j] = *(const ushort4*)&xwh[(size_t)(e[j].x & 0x07FFFFFF) * 64 + 4 * q];
#pragma unroll
      for (int j = 0; j < 8; ++j) {
        float w = __int_as_float(e[j].y);
        acc.x += relu_f(w * bf2f(u[j].x) + mbq.x);
        acc.y += relu_f(w * bf2f(u[j].y) + mbq.y);
        acc.z += relu_f(w * bf2f(u[j].z) + mbq.z);
        acc.w += relu_f(w * bf2f(u[j].w) + mbq.w);
      }
    }
    if (k + 4 <= cN) {
      int2 e[4];
#pragma unroll
      for (int j = 0; j < 4; ++j) e[j] = elist[c0 + s_idx[st + k + j]];
      ushort4 u[4];
#pragma unroll
      for (int j = 0; j < 4; ++j)
        u[j] = *(const ushort4*)&xwh[(size_t)(e[j].x & 0x07FFFFFF) * 64 + 4 * q];
#pragma unroll
      for (int j = 0; j < 4; ++j) {
        float w = __int_as_float(e[j].y);
        acc.x += relu_f(w * bf2f(u[j].x) + mbq.x);
        acc.y += relu_f(w * bf2f(u[j].y) + mbq.y);
        acc.z += relu_f(w * bf2f(u[j].z) + mbq.z);
        acc.w += relu_f(w * bf2f(u[j].w) + mbq.w);
      }
      k += 4;
    }
    for (; k < cN; ++k) {
      int2 ev = elist[c0 + s_idx[st + k]];
      ushort4 u0 = *(const ushort4*)&xwh[(size_t)(ev.x & 0x07FFFFFF) * 64 + 4 * q];
      float w = __int_as_float(ev.y);
      acc.x += relu_f(w * bf2f(u0.x) + mbq.x);
      acc.y += relu_f(w * bf2f(u0.y) + mbq.y);
      acc.z += relu_f(w * bf2f(u0.z) + mbq.z);
      acc.w += relu_f(w * bf2f(u0.w) + mbq.w);
    }
    __syncthreads();
  }
  const float inv = 1.0f / fmaxf((float)cnt_g, 1.0f);
  acc.x *= inv; acc.y *= inv; acc.z *= inv; acc.w *= inv;
  *(float4*)&s_rh[g][4 * q] = acc;
  __syncthreads();
  float4 o = make_float4(0.f, 0.f, 0.f, 0.f);
  for (int f = 0; f < 64; ++f) {
    float rv = s_rh[g][f];
    float4 wv = *(const float4*)&s_nk[f][4 * q];
    o.x += rv * wv.x; o.y += rv * wv.y; o.z += rv * wv.z; o.w += rv * wv.w;
  }
  const int loc = sub * 16 + g;
  const int n = s * sliceN + loc;
  if (loc < sliceN && n < n_nodes) {
    float4 bv = *(const float4*)&bias[4 * q];
    *(float4*)&out[(size_t)n * 128 + 4 * q] =
        make_float4(relu_f(o.x + bv.x), relu_f(o.y + bv.y),
                    relu_f(o.z + bv.z), relu_f(o.w + bv.w));
  }
}

extern "C" void kernel_launch(void* const* d_in, const int* in_sizes, int n_in,
                              void* d_out, int out_size, void* d_ws, size_t ws_size,
                              hipStream_t stream) {
  const float* x    = (const float*)d_in[0];
  const int*   ei   = (const int*)d_in[1];     // [2, E]
  const float* ew   = (const float*)d_in[2];
  const float* mk   = (const float*)d_in[3];
  const float* mb   = (const float*)d_in[4];
  const float* nk   = (const float*)d_in[5];
  const float* sk   = (const float*)d_in[6];
  const float* bias = (const float*)d_in[7];
  float* out = (float*)d_out;

  const int n_nodes = in_sizes[0] / 64;
  const int n_edges = in_sizes[2];
  const int* row = ei;
  const int* col = ei + n_edges;

  // ws layout: xwh | cnt | bcur(8) | off | bsum(128) | osub | elist | brow | bpair | hist
  unsigned short* xwh = (unsigned short*)d_ws;              // [N*64] bf16
  int*  cnt  = (int*)(xwh + (size_t)n_nodes * 64);
  int*  bcur = cnt + n_nodes;
  int*  off  = bcur + 8;
  int*  bsum = off + n_nodes;
  int*  osub = bsum + 128;                                  // [8*MAXSUB+8]
  size_t ebytes = ((size_t)((char*)(osub + 8 * MAXSUB + 8) - (char*)d_ws) + 7) & ~(size_t)7;
  int2* elist = (int2*)((char*)d_ws + ebytes);              // [E]
  const int cap = (n_edges >> 3) + 8192;                    // per-bucket capacity
  int*  brow  = (int*)(elist + n_edges);                    // [8*cap]; tier A: bpk
  size_t pboff = (((size_t)((char*)(brow + (size_t)8 * cap) - (char*)d_ws)) + 7) & ~(size_t)7;
  int2* bpair = (int2*)((char*)d_ws + pboff);               // [8*cap]; tier A: bew
  int*   bpk  = brow;
  float* bew  = (float*)bpair;
  size_t need_b = (size_t)((char*)(bpair + (size_t)8 * cap) - (char*)d_ws);
  size_t hoff = (need_b + 15) & ~(size_t)15;
  int*  hist  = (int*)((char*)d_ws + hoff);                 // [8*NBH*MAXSLICE]
  size_t need_a = hoff + (size_t)8 * NBH * MAXSLICE * sizeof(int);

  const int nb_scan = (n_nodes + 1023) / 1024;
  const int sliceN = (n_nodes + 7) >> 3;
  const int nsub = (sliceN + 15) >> 4;
  const int nbn = (n_nodes + 63) / 64;
  const int nbf = (n_nodes + 15) / 16;
  const int chunk = (cap + NBH - 1) / NBH;

  const bool fitsA = (ws_size >= need_a) && (sliceN <= MAXSLICE);
  const bool subOK = fitsA && (nsub <= MAXSUB) && (n_nodes >= 16) &&
                     (n_nodes < (1 << 17)) &&               // packed pk = col | rloc<<17
                     ((size_t)8 * cap >= (size_t)n_edges);

  if (subOK) {
    // tier A (R11 exact, measured 236.9 us): memset -> [gemm ∥ bin packed]
    // -> hist16 -> colscan16 -> place16 -> fused_sub
    hipMemsetAsync(bcur, 0, 8 * sizeof(int), stream);
    int nbb = (n_edges + 1023) / 1024;
    if (nbb > 2048) nbb = 2048;
    if (nbb < 1) nbb = 1;
    k_gemm_bin<<<nbn + nbb, 256, 0, stream>>>(x, mk, sk, bias, xwh, out, n_nodes,
                                              row, col, ew, bpk, bew, bcur,
                                              n_edges, sliceN, cap, nbn);
    k_hist16_pk<<<8 * NBH, 256, 0, stream>>>(bpk, bcur, hist, cap, chunk, sliceN);
    k_colscan16<<<8, 1024, 0, stream>>>(hist, bcur, osub, cap, sliceN);
    k_place16_pk<<<8 * NBH, 256, 0, stream>>>(bpk, bew, bcur, hist, osub,
                                              elist, cap, chunk, sliceN);
    k_fused_sub<<<8 * nsub, 256, 0, stream>>>(osub, elist, xwh, mb, nk, bias,
                                              out, n_nodes, sliceN);
  } else if (fitsA) {
    // tier B: node-level CSR (proven R3 path)
    hipMemsetAsync(bcur, 0, 8 * sizeof(int), stream);
    k_node_dual_gemm<<<nbn, 256, 0, stream>>>(x, mk, sk, bias, xwh, out, n_nodes);
    int nbb = (n_edges + 1023) / 1024;
    if (nbb > 2048) nbb = 2048;
    k_bin<<<nbb, 256, 0, stream>>>(row, col, ew, brow, bpair, bcur,
                                   n_edges, sliceN, cap);
    k_hist<<<8 * NBH, 256, 0, stream>>>(brow, bcur, hist, cap, chunk, sliceN);
    const int ncb = (sliceN + 1023) / 1024;
    k_colscan<<<8 * ncb, 256, 0, stream>>>(hist, cnt, sliceN, n_nodes);
    k_bsum<<<nb_scan, 1024, 0, stream>>>(cnt, bsum, n_nodes);
    k_boffs<<<nb_scan, 1024, 0, stream>>>(cnt, bsum, off, n_nodes, nb_scan);
    k_place<<<8 * NBH, 256, 0, stream>>>(brow, bpair, bcur, hist, off,
                                         elist, cap, chunk, sliceN, n_nodes);
    k_fused_csr<<<nbf, 256, 0, stream>>>(cnt, off, elist, xwh, mb, nk,
                                         bias, out, n_nodes, 1);
  } else {
    // tier C: original verified path
    hipMemsetAsync(cnt, 0, (size_t)n_nodes * sizeof(int), stream);
    k_node_dual_gemm<<<nbn, 256, 0, stream>>>(x, mk, sk, bias, xwh, out, n_nodes);
    const int nbe = (n_edges + 255) / 256;
    k_count<<<nbe, 256, 0, stream>>>(row, cnt, n_edges);
    k_bsum<<<nb_scan, 1024, 0, stream>>>(cnt, bsum, n_nodes);
    k_boffs<<<nb_scan, 1024, 0, stream>>>(cnt, bsum, off, n_nodes, nb_scan);
    k_build_sliced<<<1024, 256, 0, stream>>>(row, col, ew, off, elist,
                                             n_edges, n_nodes);
    k_fused_csr<<<nbf, 256, 0, stream>>>(cnt, off, elist, xwh, mb, nk,
                                         bias, out, n_nodes, 0);
  }
}

// Round 15
// 227.091 us; speedup vs baseline: 1.4301x; 1.0324x over previous
//
#include <hip/hip_runtime.h>

#define MAXSLICE 12544   // max nodes per slice (node-level tier-B path)
#define MAXSUB   800     // max 16-node subbuckets per slice (>= 12544/16)
#define NBH 32           // histogram/place chunks per slice
#define IDXCAP 512       // per-chunk in-fused sort capacity

static __device__ __forceinline__ float relu_f(float v) { return fmaxf(v, 0.f); }

// fp32 -> bf16 with round-to-nearest-even
static __device__ __forceinline__ unsigned short f2bf(float f) {
  unsigned u = __float_as_uint(f);
  u += 0x7fffu + ((u >> 16) & 1u);
  return (unsigned short)(u >> 16);
}
static __device__ __forceinline__ float bf2f(unsigned short h) {
  return __uint_as_float(((unsigned)h) << 16);
}

// ===== Mega-kernel (tier A): blocks < nbn do GEMM; rest do packed bin.
// SLIM LDS: GEMM keeps only xT (17.4 KB) in LDS; mk/sk read from global
// (32 KB total, L1/L2-resident) -> union 50.2->17.4 KB -> bin occupancy 3->~7
// blocks/CU. pk = col | rloc<<17 (n_nodes < 2^17), ew planar. =====
__global__ __launch_bounds__(256) void k_gemm_bin(
    const float* __restrict__ x, const float* __restrict__ mk,
    const float* __restrict__ sk, const float* __restrict__ bias,
    unsigned short* __restrict__ xwh, float* __restrict__ out, int n_nodes,
    const int* __restrict__ row, const int* __restrict__ col,
    const float* __restrict__ ew,
    int* __restrict__ bpk, float* __restrict__ bew, int* __restrict__ bcur,
    int n_edges, int sliceN, int cap, int nbn)
{
  __shared__ union U {
    struct { float xT[64][68]; } g;
    struct { int wcnt[4][8]; int tot[8]; int toff[8]; int gaddr[8];
             int pk[1024]; float ww[1024]; } b;
  } u;
  const int tid = threadIdx.x;

  if (blockIdx.x < nbn) {
    // ---- GEMM path (weights direct from global; x-tile transposed in LDS) ----
    const int node0 = blockIdx.x * 64;
    for (int i = tid; i < 4096; i += 256) {
      int nl = i >> 6, f = i & 63;
      int n = node0 + nl;
      u.g.xT[f][nl] = (n < n_nodes) ? x[(size_t)n * 64 + f] : 0.f;
    }
    __syncthreads();
    const int g  = tid >> 4;
    const int ub = (tid & 15) * 4;
    float am[4][4] = {{0.f}};
    float as[4][4] = {{0.f}};
    for (int f = 0; f < 64; ++f) {
      float4 wm = *(const float4*)&mk[f * 64 + ub];
      float4 ws = *(const float4*)&sk[f * 64 + ub];
      float4 xv = *(const float4*)&u.g.xT[f][4 * g];
      const float xs[4] = {xv.x, xv.y, xv.z, xv.w};
#pragma unroll
      for (int j = 0; j < 4; ++j) {
        am[j][0] += xs[j] * wm.x; am[j][1] += xs[j] * wm.y;
        am[j][2] += xs[j] * wm.z; am[j][3] += xs[j] * wm.w;
        as[j][0] += xs[j] * ws.x; as[j][1] += xs[j] * ws.y;
        as[j][2] += xs[j] * ws.z; as[j][3] += xs[j] * ws.w;
      }
    }
    float4 bv = *(const float4*)&bias[64 + ub];
#pragma unroll
    for (int j = 0; j < 4; ++j) {
      int n = node0 + 4 * g + j;
      if (n >= n_nodes) break;
      ushort4 o1 = make_ushort4(f2bf(am[j][0]), f2bf(am[j][1]),
                                f2bf(am[j][2]), f2bf(am[j][3]));
      *(ushort4*)&xwh[(size_t)n * 64 + ub] = o1;
      *(float4*)&out[(size_t)n * 128 + 64 + ub] =
          make_float4(relu_f(as[j][0] + bv.x), relu_f(as[j][1] + bv.y),
                      relu_f(as[j][2] + bv.z), relu_f(as[j][3] + bv.w));
    }
    return;
  }

  // ---- BIN path (packed records) ----
  const int vbid = blockIdx.x - nbn;
  const int nvb  = gridDim.x - nbn;
  const int wave = tid >> 6;
  const int lane = tid & 63;
  const unsigned usliceN = (unsigned)sliceN;
  const int stride = nvb * 1024;
  for (int e0 = vbid * 1024; e0 < n_edges; e0 += stride) {
    const int e = e0 + 4 * tid;
    int   pp[4];
    float ww[4];
    int   ss[4];
    if (e + 3 < n_edges) {
      int4 r4   = *(const int4*)&row[e];
      int4 c4   = *(const int4*)&col[e];
      float4 w4 = *(const float4*)&ew[e];
      int rr[4] = {r4.x, r4.y, r4.z, r4.w};
      int cc[4] = {c4.x, c4.y, c4.z, c4.w};
      ww[0] = w4.x; ww[1] = w4.y; ww[2] = w4.z; ww[3] = w4.w;
#pragma unroll
      for (int j = 0; j < 4; ++j) {
        ss[j] = (int)((unsigned)rr[j] / usliceN);
        pp[j] = cc[j] | ((rr[j] - ss[j] * sliceN) << 17);
      }
    } else {
#pragma unroll
      for (int j = 0; j < 4; ++j) {
        int ej = e + j;
        bool v = ej < n_edges;
        int r = v ? row[ej] : 0;
        int c = v ? col[ej] : 0;
        ww[j] = v ? ew[ej] : 0.f;
        ss[j] = v ? (int)((unsigned)r / usliceN) : -1;
        pp[j] = v ? (c | ((r - ss[j] * sliceN) << 17)) : 0;
      }
    }
#pragma unroll
    for (int b = 0; b < 8; ++b) {
      int c = 0;
#pragma unroll
      for (int j = 0; j < 4; ++j) c += __popcll(__ballot(ss[j] == b));
      if (lane == 0) u.b.wcnt[wave][b] = c;
    }
    __syncthreads();
    if (wave == 0 && lane < 8) {
      const int b = lane;
      int t0 = u.b.wcnt[0][b], t1 = u.b.wcnt[1][b];
      int t2 = u.b.wcnt[2][b], t3 = u.b.wcnt[3][b];
      int tot = t0 + t1 + t2 + t3;
      u.b.tot[b] = tot;
      u.b.wcnt[0][b] = 0;
      u.b.wcnt[1][b] = t0;
      u.b.wcnt[2][b] = t0 + t1;
      u.b.wcnt[3][b] = t0 + t1 + t2;
      int gbase = tot ? atomicAdd(&bcur[b], tot) : 0;
      int pre = 0;
#pragma unroll
      for (int j2 = 0; j2 < 8; ++j2) pre += (j2 < b) ? u.b.tot[j2] : 0;
      u.b.toff[b]  = pre;
      u.b.gaddr[b] = b * cap + gbase - pre;
    }
    __syncthreads();
#pragma unroll
    for (int b = 0; b < 8; ++b) {
      const int sb = u.b.toff[b] + u.b.wcnt[wave][b];
      int off_local = 0;
#pragma unroll
      for (int j = 0; j < 4; ++j) {
        unsigned long long mm = __ballot(ss[j] == b);
        if (ss[j] == b) {
          int rank = __popcll(mm & ((1ull << lane) - 1ull));
          int slot = sb + off_local + rank;
          u.b.pk[slot] = pp[j];
          u.b.ww[slot] = ww[j];
        }
        off_local += __popcll(mm);
      }
    }
    __syncthreads();
    const int total = u.b.toff[7] + u.b.tot[7];
    for (int i2 = tid; i2 < total; i2 += 256) {
      int b = 0;
#pragma unroll
      for (int j2 = 1; j2 < 8; ++j2) b += (i2 >= u.b.toff[j2]) ? 1 : 0;
      int a = u.b.gaddr[b] + i2;
      if (a < (b + 1) * cap) {
        bpk[a] = u.b.pk[i2];
        bew[a] = u.b.ww[i2];
      }
    }
    __syncthreads();
  }
}

// Standalone GEMM (tiers B/C)
__global__ __launch_bounds__(256) void k_node_dual_gemm(
    const float* __restrict__ x, const float* __restrict__ mk,
    const float* __restrict__ sk, const float* __restrict__ bias,
    unsigned short* __restrict__ xwh, float* __restrict__ out, int n_nodes)
{
  __shared__ float s_mk[64][64];
  __shared__ float s_sk[64][64];
  __shared__ float s_xT[64][68];
  const int tid = threadIdx.x;
  for (int i = tid; i < 4096; i += 256) {
    s_mk[i >> 6][i & 63] = mk[i];
    s_sk[i >> 6][i & 63] = sk[i];
  }
  const int node0 = blockIdx.x * 64;
  for (int i = tid; i < 4096; i += 256) {
    int nl = i >> 6, f = i & 63;
    int n = node0 + nl;
    s_xT[f][nl] = (n < n_nodes) ? x[(size_t)n * 64 + f] : 0.f;
  }
  __syncthreads();
  const int g  = tid >> 4;
  const int ub = (tid & 15) * 4;
  float am[4][4] = {{0.f}};
  float as[4][4] = {{0.f}};
  for (int f = 0; f < 64; ++f) {
    float4 wm = *(const float4*)&s_mk[f][ub];
    float4 ws = *(const float4*)&s_sk[f][ub];
    float4 xv = *(const float4*)&s_xT[f][4 * g];
    const float xs[4] = {xv.x, xv.y, xv.z, xv.w};
#pragma unroll
    for (int j = 0; j < 4; ++j) {
      am[j][0] += xs[j] * wm.x; am[j][1] += xs[j] * wm.y;
      am[j][2] += xs[j] * wm.z; am[j][3] += xs[j] * wm.w;
      as[j][0] += xs[j] * ws.x; as[j][1] += xs[j] * ws.y;
      as[j][2] += xs[j] * ws.z; as[j][3] += xs[j] * ws.w;
    }
  }
  float4 bv = *(const float4*)&bias[64 + ub];
#pragma unroll
  for (int j = 0; j < 4; ++j) {
    int n = node0 + 4 * g + j;
    if (n >= n_nodes) break;
    ushort4 o1 = make_ushort4(f2bf(am[j][0]), f2bf(am[j][1]),
                              f2bf(am[j][2]), f2bf(am[j][3]));
    *(ushort4*)&xwh[(size_t)n * 64 + ub] = o1;
    *(float4*)&out[(size_t)n * 128 + 64 + ub] =
        make_float4(relu_f(as[j][0] + bv.x), relu_f(as[j][1] + bv.y),
                    relu_f(as[j][2] + bv.z), relu_f(as[j][3] + bv.w));
  }
}

// ---------- tier C (original path) ----------
__global__ __launch_bounds__(256) void k_count(
    const int* __restrict__ row, int* __restrict__ cnt, int n_edges)
{
  int e = blockIdx.x * 256 + threadIdx.x;
  if (e < n_edges) atomicAdd(&cnt[row[e]], 1);
}

__global__ __launch_bounds__(256) void k_build_sliced(
    const int* __restrict__ row, const int* __restrict__ col,
    const float* __restrict__ ew, int* __restrict__ off,
    int2* __restrict__ elist, int n_edges, int n_nodes)
{
  const int slice = blockIdx.x & 7;
  const int vb    = blockIdx.x >> 3;
  const int nvb   = gridDim.x >> 3;
  const int sliceN = (n_nodes + 7) >> 3;
  const int lo = slice * sliceN;
  const int hi = min(lo + sliceN, n_nodes);
  for (int e = vb * 256 + threadIdx.x; e < n_edges; e += nvb * 256) {
    int r = row[e];
    if (r >= lo && r < hi) {
      int pos = atomicAdd(&off[r], 1);
      elist[pos] = make_int2(col[e], __float_as_int(ew[e]));
    }
  }
}
// ---------- end tier C ----------

// Scan step 1: per-1024-block sums of cnt.
__global__ __launch_bounds__(1024) void k_bsum(
    const int* __restrict__ cnt, int* __restrict__ bsum, int n)
{
  __shared__ int s[1024];
  int tid = threadIdx.x;
  int i = blockIdx.x * 1024 + tid;
  s[tid] = (i < n) ? cnt[i] : 0;
  __syncthreads();
  for (int d = 512; d > 0; d >>= 1) {
    if (tid < d) s[tid] += s[tid + d];
    __syncthreads();
  }
  if (tid == 0) bsum[blockIdx.x] = s[0];
}

// Scan step 2: block-local exclusive scan of cnt + block prefix from bsum.
__global__ __launch_bounds__(1024) void k_boffs(
    const int* __restrict__ cnt, const int* __restrict__ bsum,
    int* __restrict__ off, int n, int nb)
{
  __shared__ int s[1024];
  __shared__ int sp[128];
  int tid = threadIdx.x;
  if (tid < 128) {
    int acc = 0;
    for (int j = tid; j < blockIdx.x && j < nb; j += 128) acc += bsum[j];
    sp[tid] = acc;
  }
  int i = blockIdx.x * 1024 + tid;
  int v = (i < n) ? cnt[i] : 0;
  s[tid] = v;
  __syncthreads();
  for (int d = 64; d > 0; d >>= 1) {
    if (tid < d) sp[tid] += sp[tid + d];
    __syncthreads();
  }
  for (int d = 1; d < 1024; d <<= 1) {
    int t = (tid >= d) ? s[tid - d] : 0;
    __syncthreads();
    s[tid] += t;
    __syncthreads();
  }
  if (i < n) off[i] = s[tid] - v + sp[0];
}

// Pass B (tier B, full records): [HW-verified R6/R7/R8]
__global__ __launch_bounds__(256) void k_bin(
    const int* __restrict__ row, const int* __restrict__ col,
    const float* __restrict__ ew,
    int* __restrict__ brow, int2* __restrict__ bpair,
    int* __restrict__ bcur, int n_edges, int sliceN, int cap)
{
  __shared__ int  s_wcnt[4][8];
  __shared__ int  s_tot[8];
  __shared__ int  s_toff[8];
  __shared__ int  s_gaddr[8];
  __shared__ int  s_rowst[1024];
  __shared__ int2 s_pairst[1024];
  const int tid  = threadIdx.x;
  const int wave = tid >> 6;
  const int lane = tid & 63;
  const unsigned usliceN = (unsigned)sliceN;
  const int stride = gridDim.x * 1024;
  for (int e0 = blockIdx.x * 1024; e0 < n_edges; e0 += stride) {
    const int e = e0 + 4 * tid;
    int   rr[4], cc[4];
    float ww[4];
    int   ss[4];
    if (e + 3 < n_edges) {
      int4 r4   = *(const int4*)&row[e];
      int4 c4   = *(const int4*)&col[e];
      float4 w4 = *(const float4*)&ew[e];
      rr[0] = r4.x; rr[1] = r4.y; rr[2] = r4.z; rr[3] = r4.w;
      cc[0] = c4.x; cc[1] = c4.y; cc[2] = c4.z; cc[3] = c4.w;
      ww[0] = w4.x; ww[1] = w4.y; ww[2] = w4.z; ww[3] = w4.w;
#pragma unroll
      for (int j = 0; j < 4; ++j) ss[j] = (int)((unsigned)rr[j] / usliceN);
    } else {
#pragma unroll
      for (int j = 0; j < 4; ++j) {
        int ej = e + j;
        bool v = ej < n_edges;
        rr[j] = v ? row[ej] : 0;
        cc[j] = v ? col[ej] : 0;
        ww[j] = v ? ew[ej]  : 0.f;
        ss[j] = v ? (int)((unsigned)rr[j] / usliceN) : -1;
      }
    }
#pragma unroll
    for (int b = 0; b < 8; ++b) {
      int c = 0;
#pragma unroll
      for (int j = 0; j < 4; ++j) c += __popcll(__ballot(ss[j] == b));
      if (lane == 0) s_wcnt[wave][b] = c;
    }
    __syncthreads();
    if (wave == 0 && lane < 8) {
      const int b = lane;
      int t0 = s_wcnt[0][b], t1 = s_wcnt[1][b], t2 = s_wcnt[2][b], t3 = s_wcnt[3][b];
      int tot = t0 + t1 + t2 + t3;
      s_tot[b] = tot;
      s_wcnt[0][b] = 0;
      s_wcnt[1][b] = t0;
      s_wcnt[2][b] = t0 + t1;
      s_wcnt[3][b] = t0 + t1 + t2;
      int gbase = tot ? atomicAdd(&bcur[b], tot) : 0;
      int pre = 0;
#pragma unroll
      for (int j2 = 0; j2 < 8; ++j2) pre += (j2 < b) ? s_tot[j2] : 0;
      s_toff[b]  = pre;
      s_gaddr[b] = b * cap + gbase - pre;
    }
    __syncthreads();
#pragma unroll
    for (int b = 0; b < 8; ++b) {
      const int sb = s_toff[b] + s_wcnt[wave][b];
      int off_local = 0;
#pragma unroll
      for (int j = 0; j < 4; ++j) {
        unsigned long long mm = __ballot(ss[j] == b);
        if (ss[j] == b) {
          int rank = __popcll(mm & ((1ull << lane) - 1ull));
          int slot = sb + off_local + rank;
          s_rowst[slot]  = rr[j];
          s_pairst[slot] = make_int2(cc[j], __float_as_int(ww[j]));
        }
        off_local += __popcll(mm);
      }
    }
    __syncthreads();
    const int total = s_toff[7] + s_tot[7];
    for (int i2 = tid; i2 < total; i2 += 256) {
      int b = 0;
#pragma unroll
      for (int j2 = 1; j2 < 8; ++j2) b += (i2 >= s_toff[j2]) ? 1 : 0;
      int a = s_gaddr[b] + i2;
      if (a < (b + 1) * cap) {
        brow[a]  = s_rowst[i2];
        bpair[a] = s_pairst[i2];
      }
    }
    __syncthreads();
  }
}

// ===================== tier B (node-level CSR, proven R3 path) =====================
__global__ __launch_bounds__(256) void k_hist(
    const int* __restrict__ brow, const int* __restrict__ bcur,
    int* __restrict__ hist, int cap, int chunk, int sliceN)
{
  __shared__ int h[MAXSLICE];
  const int s   = blockIdx.x & 7;
  const int blk = blockIdx.x >> 3;
  const int tid = threadIdx.x;
  for (int i = tid; i < MAXSLICE; i += 256) h[i] = 0;
  __syncthreads();
  const int n_s  = min(bcur[s], cap);
  const int lo_e = blk * chunk;
  const int hi_e = min(lo_e + chunk, n_s);
  const int base = s * cap;
  const int lo   = s * sliceN;
  for (int i = lo_e + tid; i < hi_e; i += 256) {
    atomicAdd(&h[brow[base + i] - lo], 1);
  }
  __syncthreads();
  int* hrow = hist + (size_t)(s * NBH + blk) * MAXSLICE;
  for (int i = tid; i < MAXSLICE / 4; i += 256) {
    ((int4*)hrow)[i] = ((const int4*)h)[i];
  }
}

__global__ __launch_bounds__(256) void k_colscan(
    int* __restrict__ hist, int* __restrict__ cnt, int sliceN, int n_nodes)
{
  const int s  = blockIdx.x & 7;
  const int cb = blockIdx.x >> 3;
  const int b0 = cb * 1024 + threadIdx.x * 4;
  if (b0 >= sliceN) return;
  int4 acc = make_int4(0, 0, 0, 0);
  int* hs = hist + (size_t)s * NBH * MAXSLICE;
#pragma unroll 4
  for (int blk = 0; blk < NBH; ++blk) {
    int4* p = (int4*)(hs + (size_t)blk * MAXSLICE + b0);
    int4 v = *p;
    *p = acc;
    acc.x += v.x; acc.y += v.y; acc.z += v.z; acc.w += v.w;
  }
  const int node = s * sliceN + b0;
  if (b0 + 3 < sliceN && node + 3 < n_nodes) {
    *(int4*)&cnt[node] = acc;
  } else {
    int a[4] = {acc.x, acc.y, acc.z, acc.w};
    for (int j = 0; j < 4; ++j)
      if (b0 + j < sliceN && node + j < n_nodes) cnt[node + j] = a[j];
  }
}

__global__ __launch_bounds__(256) void k_place(
    const int* __restrict__ brow, const int2* __restrict__ bpair,
    const int* __restrict__ bcur, const int* __restrict__ hist,
    const int* __restrict__ off, int2* __restrict__ elist,
    int cap, int chunk, int sliceN, int n_nodes)
{
  __shared__ int cur[MAXSLICE];
  const int s   = blockIdx.x & 7;
  const int blk = blockIdx.x >> 3;
  const int tid = threadIdx.x;
  const int lo  = s * sliceN;
  const int hi  = min(lo + sliceN, n_nodes);
  const int nb  = hi - lo;
  const int* hrow = hist + (size_t)(s * NBH + blk) * MAXSLICE;
  for (int i = tid; i < nb; i += 256) cur[i] = off[lo + i] + hrow[i];
  __syncthreads();
  const int n_s  = min(bcur[s], cap);
  const int lo_e = blk * chunk;
  const int hi_e = min(lo_e + chunk, n_s);
  const int base = s * cap;
  for (int i = lo_e + tid; i < hi_e; i += 256) {
    int r = brow[base + i] - lo;
    int p = atomicAdd(&cur[r], 1);
    elist[p] = bpair[base + i];
  }
}

// R3's proven fused kernel (tier B/C): per-node 16-lane groups, 8-deep unroll.
__global__ __launch_bounds__(256) void k_fused_csr(
    const int* __restrict__ cnt, const int* __restrict__ off,
    const int2* __restrict__ elist, const unsigned short* __restrict__ xwh,
    const float* __restrict__ mb, const float* __restrict__ nk,
    const float* __restrict__ bias, float* __restrict__ out, int n_nodes,
    int starts)
{
  __shared__ float s_nk[64][64];
  __shared__ float s_rh[16][68];
  const int tid = threadIdx.x;
  for (int i = tid; i < 1024; i += 256) {
    *(float4*)&s_nk[0][4 * i] = *(const float4*)&nk[4 * i];
  }
  const int node_l = tid >> 4;
  const int q = tid & 15;
  const int n = blockIdx.x * 16 + node_l;
  float4 acc = make_float4(0.f, 0.f, 0.f, 0.f);
  if (n < n_nodes) {
    const float4 mbq = *(const float4*)&mb[4 * q];
    const int c = cnt[n];
    int i = off[n] - (starts ? 0 : c);
    const int end = i + c;
    for (; i + 8 <= end; i += 8) {
      int2 e[8];
#pragma unroll
      for (int j = 0; j < 8; ++j) e[j] = elist[i + j];
      ushort4 u[8];
#pragma unroll
      for (int j = 0; j < 8; ++j)
        u[j] = *(const ushort4*)&xwh[(size_t)e[j].x * 64 + 4 * q];
#pragma unroll
      for (int j = 0; j < 8; ++j) {
        float w = __int_as_float(e[j].y);
        acc.x += relu_f(w * bf2f(u[j].x) + mbq.x);
        acc.y += relu_f(w * bf2f(u[j].y) + mbq.y);
        acc.z += relu_f(w * bf2f(u[j].z) + mbq.z);
        acc.w += relu_f(w * bf2f(u[j].w) + mbq.w);
      }
    }
    if (i + 4 <= end) {
      int2 e[4];
#pragma unroll
      for (int j = 0; j < 4; ++j) e[j] = elist[i + j];
      ushort4 u[4];
#pragma unroll
      for (int j = 0; j < 4; ++j)
        u[j] = *(const ushort4*)&xwh[(size_t)e[j].x * 64 + 4 * q];
#pragma unroll
      for (int j = 0; j < 4; ++j) {
        float w = __int_as_float(e[j].y);
        acc.x += relu_f(w * bf2f(u[j].x) + mbq.x);
        acc.y += relu_f(w * bf2f(u[j].y) + mbq.y);
        acc.z += relu_f(w * bf2f(u[j].z) + mbq.z);
        acc.w += relu_f(w * bf2f(u[j].w) + mbq.w);
      }
      i += 4;
    }
    for (; i < end; ++i) {
      int2 e0 = elist[i];
      ushort4 u0 = *(const ushort4*)&xwh[(size_t)e0.x * 64 + 4 * q];
      float w0 = __int_as_float(e0.y);
      acc.x += relu_f(w0 * bf2f(u0.x) + mbq.x);
      acc.y += relu_f(w0 * bf2f(u0.y) + mbq.y);
      acc.z += relu_f(w0 * bf2f(u0.z) + mbq.z);
      acc.w += relu_f(w0 * bf2f(u0.w) + mbq.w);
    }
    const float inv = 1.0f / fmaxf((float)c, 1.0f);
    acc.x *= inv; acc.y *= inv; acc.z *= inv; acc.w *= inv;
  }
  *(float4*)&s_rh[node_l][4 * q] = acc;
  __syncthreads();
  float4 o = make_float4(0.f, 0.f, 0.f, 0.f);
  for (int f = 0; f < 64; ++f) {
    float rv = s_rh[node_l][f];
    float4 wv = *(const float4*)&s_nk[f][4 * q];
    o.x += rv * wv.x; o.y += rv * wv.y; o.z += rv * wv.z; o.w += rv * wv.w;
  }
  if (n < n_nodes) {
    float4 bv = *(const float4*)&bias[4 * q];
    *(float4*)&out[(size_t)n * 128 + 4 * q] =
        make_float4(relu_f(o.x + bv.x), relu_f(o.y + bv.y),
                    relu_f(o.z + bv.z), relu_f(o.w + bv.w));
  }
}

// ===================== tier A kernels (packed-record, R11/R14-verified) ==========
// hist over 16-node subbuckets from packed records: sub = pk>>21.
__global__ __launch_bounds__(256) void k_hist16_pk(
    const int* __restrict__ bpk, const int* __restrict__ bcur,
    int* __restrict__ hist, int cap, int chunk, int sliceN)
{
  __shared__ int h[MAXSUB];
  const int s   = blockIdx.x & 7;
  const int blk = blockIdx.x >> 3;
  const int tid = threadIdx.x;
  const int nsub = (sliceN + 15) >> 4;
  for (int i = tid; i < nsub; i += 256) h[i] = 0;
  __syncthreads();
  const int n_s  = min(bcur[s], cap);
  const int lo_e = blk * chunk;
  const int hi_e = min(lo_e + chunk, n_s);
  const int base = s * cap;
  for (int i = lo_e + tid; i < hi_e; i += 256) {
    atomicAdd(&h[((unsigned)bpk[base + i]) >> 21], 1);
  }
  __syncthreads();
  int* hrow = hist + (size_t)(s * NBH + blk) * MAXSUB;
  for (int i = tid; i < nsub; i += 256) hrow[i] = h[i];
}

// colscan16: [HW-verified R6/R7/R8/R11/R14]
__global__ __launch_bounds__(1024) void k_colscan16(
    int* __restrict__ hist, const int* __restrict__ bcur,
    int* __restrict__ off_sub, int cap, int sliceN)
{
  __shared__ int s_t[1024];
  const int s = blockIdx.x;
  const int tid = threadIdx.x;
  const int nsub = (sliceN + 15) >> 4;
  int acc = 0;
  if (tid < nsub) {
    int* hs = hist + (size_t)s * NBH * MAXSUB;
    for (int blk = 0; blk < NBH; ++blk) {
      int* p = hs + (size_t)blk * MAXSUB + tid;
      int v = *p;
      *p = acc;
      acc += v;
    }
  }
  s_t[tid] = (tid < nsub) ? acc : 0;
  __syncthreads();
  for (int d = 1; d < 1024; d <<= 1) {
    int t = (tid >= d) ? s_t[tid - d] : 0;
    __syncthreads();
    s_t[tid] += t;
    __syncthreads();
  }
  int base = 0;
  for (int b = 0; b < s; ++b) base += min(bcur[b], cap);
  int excl = (tid == 0) ? 0 : s_t[tid - 1];
  if (tid < nsub) off_sub[s * nsub + tid] = base + excl;
  if (s == 7 && tid == 1023) off_sub[8 * nsub] = base + s_t[1023];
}

// place16 from packed records: cur[pk>>21]; elist = (col | (rloc&15)<<27, ew).
__global__ __launch_bounds__(256) void k_place16_pk(
    const int* __restrict__ bpk, const float* __restrict__ bew,
    const int* __restrict__ bcur, const int* __restrict__ hist,
    const int* __restrict__ off_sub, int2* __restrict__ elist,
    int cap, int chunk, int sliceN)
{
  __shared__ int cur[MAXSUB];
  const int s   = blockIdx.x & 7;
  const int blk = blockIdx.x >> 3;
  const int tid = threadIdx.x;
  const int nsub = (sliceN + 15) >> 4;
  const int* hrow = hist + (size_t)(s * NBH + blk) * MAXSUB;
  for (int i = tid; i < nsub; i += 256) cur[i] = off_sub[s * nsub + i] + hrow[i];
  __syncthreads();
  const int n_s  = min(bcur[s], cap);
  const int lo_e = blk * chunk;
  const int hi_e = min(lo_e + chunk, n_s);
  const int base = s * cap;
  for (int i = lo_e + tid; i < hi_e; i += 256) {
    unsigned pk = (unsigned)bpk[base + i];
    float w = bew[base + i];
    int p = atomicAdd(&cur[pk >> 21], 1);
    elist[p] = make_int2((int)((pk & 0x1FFFFu) | (((pk >> 17) & 15u) << 27)),
                         __float_as_int(w));
  }
}

// Fused with in-block sort (HW-verified R8/R10/R11/R12/R14, 62-68 us). UNCHANGED.
__global__ __launch_bounds__(256) void k_fused_sub(
    const int* __restrict__ osub, const int2* __restrict__ elist,
    const unsigned short* __restrict__ xwh, const float* __restrict__ mb,
    const float* __restrict__ nk, const float* __restrict__ bias,
    float* __restrict__ out, int n_nodes, int sliceN)
{
  __shared__ float s_nk[64][64];
  __shared__ float s_rh[16][68];
  __shared__ int s_h[16];
  __shared__ int s_pre[17];
  __shared__ int s_cur[16];
  __shared__ unsigned short s_idx[IDXCAP];
  const int tid = threadIdx.x;
  for (int i = tid; i < 1024; i += 256) {
    *(float4*)&s_nk[0][4 * i] = *(const float4*)&nk[4 * i];
  }
  const int s   = blockIdx.x & 7;
  const int sub = blockIdx.x >> 3;
  const int nsub = (sliceN + 15) >> 4;
  const int e0 = osub[s * nsub + sub];
  const int e1 = osub[s * nsub + sub + 1];
  const int g = tid >> 4;
  const int q = tid & 15;
  const float4 mbq = *(const float4*)&mb[4 * q];
  float4 acc = make_float4(0.f, 0.f, 0.f, 0.f);
  int cnt_g = 0;
  for (int c0 = e0; c0 < e1; c0 += IDXCAP) {
    const int m = min(IDXCAP, e1 - c0);
    if (tid < 16) s_h[tid] = 0;
    __syncthreads();
    for (int i = tid; i < m; i += 256) {
      atomicAdd(&s_h[((unsigned)elist[c0 + i].x) >> 27], 1);
    }
    __syncthreads();
    if (tid == 0) {
      int a = 0;
#pragma unroll
      for (int b = 0; b < 16; ++b) { s_pre[b] = a; s_cur[b] = a; a += s_h[b]; }
      s_pre[16] = a;
    }
    __syncthreads();
    for (int i = tid; i < m; i += 256) {
      int rl = ((unsigned)elist[c0 + i].x) >> 27;
      int p = atomicAdd(&s_cur[rl], 1);
      s_idx[p] = (unsigned short)i;
    }
    __syncthreads();
    const int st = s_pre[g];
    const int cN = s_h[g];
    cnt_g += cN;
    int k = 0;
    for (; k + 8 <= cN; k += 8) {
      int2 e[8];
#pragma unroll
      for (int j = 0; j < 8; ++j) e[j] = elist[c0 + s_idx[st + k + j]];
      ushort4 u[8];
#pragma unroll
      for (int j = 0; j < 8; ++j)
        u[j] = *(const ushort4*)&xwh[(size_t)(e[j].x & 0x07FFFFFF) * 64 + 4 * q];
#pragma unroll
      for (int j = 0; j < 8; ++j) {
        float w = __int_as_float(e[j].y);
        acc.x += relu_f(w * bf2f(u[j].x) + mbq.x);
        acc.y += relu_f(w * bf2f(u[j].y) + mbq.y);
        acc.z += relu_f(w * bf2f(u[j].z) + mbq.z);
        acc.w += relu_f(w * bf2f(u[j].w) + mbq.w);
      }
    }
    if (k + 4 <= cN) {
      int2 e[4];
#pragma unroll
      for (int j = 0; j < 4; ++j) e[j] = elist[c0 + s_idx[st + k + j]];
      ushort4 u[4];
#pragma unroll
      for (int j = 0; j < 4; ++j)
        u[j] = *(const ushort4*)&xwh[(size_t)(e[j].x & 0x07FFFFFF) * 64 + 4 * q];
#pragma unroll
      for (int j = 0; j < 4; ++j) {
        float w = __int_as_float(e[j].y);
        acc.x += relu_f(w * bf2f(u[j].x) + mbq.x);
        acc.y += relu_f(w * bf2f(u[j].y) + mbq.y);
        acc.z += relu_f(w * bf2f(u[j].z) + mbq.z);
        acc.w += relu_f(w * bf2f(u[j].w) + mbq.w);
      }
      k += 4;
    }
    for (; k < cN; ++k) {
      int2 ev = elist[c0 + s_idx[st + k]];
      ushort4 u0 = *(const ushort4*)&xwh[(size_t)(ev.x & 0x07FFFFFF) * 64 + 4 * q];
      float w = __int_as_float(ev.y);
      acc.x += relu_f(w * bf2f(u0.x) + mbq.x);
      acc.y += relu_f(w * bf2f(u0.y) + mbq.y);
      acc.z += relu_f(w * bf2f(u0.z) + mbq.z);
      acc.w += relu_f(w * bf2f(u0.w) + mbq.w);
    }
    __syncthreads();
  }
  const float inv = 1.0f / fmaxf((float)cnt_g, 1.0f);
  acc.x *= inv; acc.y *= inv; acc.z *= inv; acc.w *= inv;
  *(float4*)&s_rh[g][4 * q] = acc;
  __syncthreads();
  float4 o = make_float4(0.f, 0.f, 0.f, 0.f);
  for (int f = 0; f < 64; ++f) {
    float rv = s_rh[g][f];
    float4 wv = *(const float4*)&s_nk[f][4 * q];
    o.x += rv * wv.x; o.y += rv * wv.y; o.z += rv * wv.z; o.w += rv * wv.w;
  }
  const int loc = sub * 16 + g;
  const int n = s * sliceN + loc;
  if (loc < sliceN && n < n_nodes) {
    float4 bv = *(const float4*)&bias[4 * q];
    *(float4*)&out[(size_t)n * 128 + 4 * q] =
        make_float4(relu_f(o.x + bv.x), relu_f(o.y + bv.y),
                    relu_f(o.z + bv.z), relu_f(o.w + bv.w));
  }
}

extern "C" void kernel_launch(void* const* d_in, const int* in_sizes, int n_in,
                              void* d_out, int out_size, void* d_ws, size_t ws_size,
                              hipStream_t stream) {
  const float* x    = (const float*)d_in[0];
  const int*   ei   = (const int*)d_in[1];     // [2, E]
  const float* ew   = (const float*)d_in[2];
  const float* mk   = (const float*)d_in[3];
  const float* mb   = (const float*)d_in[4];
  const float* nk   = (const float*)d_in[5];
  const float* sk   = (const float*)d_in[6];
  const float* bias = (const float*)d_in[7];
  float* out = (float*)d_out;

  const int n_nodes = in_sizes[0] / 64;
  const int n_edges = in_sizes[2];
  const int* row = ei;
  const int* col = ei + n_edges;

  // ws layout: xwh | cnt | bcur(8) | off | bsum(128) | osub | elist | brow | bpair | hist
  unsigned short* xwh = (unsigned short*)d_ws;              // [N*64] bf16
  int*  cnt  = (int*)(xwh + (size_t)n_nodes * 64);
  int*  bcur = cnt + n_nodes;
  int*  off  = bcur + 8;
  int*  bsum = off + n_nodes;
  int*  osub = bsum + 128;                                  // [8*MAXSUB+8]
  size_t ebytes = ((size_t)((char*)(osub + 8 * MAXSUB + 8) - (char*)d_ws) + 7) & ~(size_t)7;
  int2* elist = (int2*)((char*)d_ws + ebytes);              // [E]
  const int cap = (n_edges >> 3) + 8192;                    // per-bucket capacity
  int*  brow  = (int*)(elist + n_edges);                    // [8*cap]; tier A: bpk
  size_t pboff = (((size_t)((char*)(brow + (size_t)8 * cap) - (char*)d_ws)) + 7) & ~(size_t)7;
  int2* bpair = (int2*)((char*)d_ws + pboff);               // [8*cap]; tier A: bew
  int*   bpk  = brow;
  float* bew  = (float*)bpair;
  size_t need_b = (size_t)((char*)(bpair + (size_t)8 * cap) - (char*)d_ws);
  size_t hoff = (need_b + 15) & ~(size_t)15;
  int*  hist  = (int*)((char*)d_ws + hoff);                 // [8*NBH*MAXSLICE]
  size_t need_a = hoff + (size_t)8 * NBH * MAXSLICE * sizeof(int);

  const int nb_scan = (n_nodes + 1023) / 1024;
  const int sliceN = (n_nodes + 7) >> 3;
  const int nsub = (sliceN + 15) >> 4;
  const int nbn = (n_nodes + 63) / 64;
  const int nbf = (n_nodes + 15) / 16;
  const int chunk = (cap + NBH - 1) / NBH;

  const bool fitsA = (ws_size >= need_a) && (sliceN <= MAXSLICE);
  const bool subOK = fitsA && (nsub <= MAXSUB) && (n_nodes >= 16) &&
                     (n_nodes < (1 << 17)) &&               // packed pk = col | rloc<<17
                     ((size_t)8 * cap >= (size_t)n_edges);

  if (subOK) {
    // tier A (R14 structure + slim GEMM LDS): memset -> [gemm ∥ bin packed]
    // -> hist16 -> colscan16 -> place16 -> fused_sub
    hipMemsetAsync(bcur, 0, 8 * sizeof(int), stream);
    int nbb = (n_edges + 1023) / 1024;
    if (nbb > 2048) nbb = 2048;
    if (nbb < 1) nbb = 1;
    k_gemm_bin<<<nbn + nbb, 256, 0, stream>>>(x, mk, sk, bias, xwh, out, n_nodes,
                                              row, col, ew, bpk, bew, bcur,
                                              n_edges, sliceN, cap, nbn);
    k_hist16_pk<<<8 * NBH, 256, 0, stream>>>(bpk, bcur, hist, cap, chunk, sliceN);
    k_colscan16<<<8, 1024, 0, stream>>>(hist, bcur, osub, cap, sliceN);
    k_place16_pk<<<8 * NBH, 256, 0, stream>>>(bpk, bew, bcur, hist, osub,
                                              elist, cap, chunk, sliceN);
    k_fused_sub<<<8 * nsub, 256, 0, stream>>>(osub, elist, xwh, mb, nk, bias,
                                              out, n_nodes, sliceN);
  } else if (fitsA) {
    // tier B: node-level CSR (proven R3 path)
    hipMemsetAsync(bcur, 0, 8 * sizeof(int), stream);
    k_node_dual_gemm<<<nbn, 256, 0, stream>>>(x, mk, sk, bias, xwh, out, n_nodes);
    int nbb = (n_edges + 1023) / 1024;
    if (nbb > 2048) nbb = 2048;
    k_bin<<<nbb, 256, 0, stream>>>(row, col, ew, brow, bpair, bcur,
                                   n_edges, sliceN, cap);
    k_hist<<<8 * NBH, 256, 0, stream>>>(brow, bcur, hist, cap, chunk, sliceN);
    const int ncb = (sliceN + 1023) / 1024;
    k_colscan<<<8 * ncb, 256, 0, stream>>>(hist, cnt, sliceN, n_nodes);
    k_bsum<<<nb_scan, 1024, 0, stream>>>(cnt, bsum, n_nodes);
    k_boffs<<<nb_scan, 1024, 0, stream>>>(cnt, bsum, off, n_nodes, nb_scan);
    k_place<<<8 * NBH, 256, 0, stream>>>(brow, bpair, bcur, hist, off,
                                         elist, cap, chunk, sliceN, n_nodes);
    k_fused_csr<<<nbf, 256, 0, stream>>>(cnt, off, elist, xwh, mb, nk,
                                         bias, out, n_nodes, 1);
  } else {
    // tier C: original verified path
    hipMemsetAsync(cnt, 0, (size_t)n_nodes * sizeof(int), stream);
    k_node_dual_gemm<<<nbn, 256, 0, stream>>>(x, mk, sk, bias, xwh, out, n_nodes);
    const int nbe = (n_edges + 255) / 256;
    k_count<<<nbe, 256, 0, stream>>>(row, cnt, n_edges);
    k_bsum<<<nb_scan, 1024, 0, stream>>>(cnt, bsum, n_nodes);
    k_boffs<<<nb_scan, 1024, 0, stream>>>(cnt, bsum, off, n_nodes, nb_scan);
    k_build_sliced<<<1024, 256, 0, stream>>>(row, col, ew, off, elist,
                                             n_edges, n_nodes);
    k_fused_csr<<<nbf, 256, 0, stream>>>(cnt, off, elist, xwh, mb, nk,
                                         bias, out, n_nodes, 0);
  }
}